// Round 5
// baseline (409.090 us; speedup 1.0000x reference)
//
#include <hip/hip_runtime.h>
#include <hip/hip_bf16.h>

#define B 16
#define T 128
#define D 256
#define H 64
#define C1 64
#define C2 20
#define K2 4096   // H*C1
#define F2 1280   // H*C2
#define OUTW 32
#define ALPHA 0.2f

typedef __attribute__((ext_vector_type(8))) short short8;
typedef __attribute__((ext_vector_type(4))) float f32x4;

static __device__ __forceinline__ ushort f2bf(float f) {
    __hip_bfloat16 h = __float2bfloat16(f);
    return *reinterpret_cast<ushort*>(&h);
}

// ---------------------------------------------------------------------------
// Templated MFMA GEMM: C[m][n] = sum_k A[m][k]*Bt[n][k] + bias[n]
// (verified round 2/4) — still used for gemm2 (K=4096) and sl (K=1280).
// ---------------------------------------------------------------------------
template<int KD, int NBLK>
__global__ __launch_bounds__(256) void gemm_bf16_kernel(
    const ushort* __restrict__ Ag, const ushort* __restrict__ Bg,
    const float* __restrict__ bias, float* __restrict__ Cm)
{
    __shared__ ushort As[128][72];
    __shared__ ushort Bs[128][72];
    const int NN = NBLK * 128;
    int tid = threadIdx.x;
    int bm = (blockIdx.x / NBLK) * 128, bn = (blockIdx.x % NBLK) * 128;
    int wave = tid >> 6, lane = tid & 63;
    int wm = (wave >> 1) * 64, wn = (wave & 1) * 64;
    int lr = lane & 15, lk = lane >> 4;
    int sr = tid >> 3, sc = (tid & 7) * 8;

    f32x4 acc[4][4];
    #pragma unroll
    for (int i = 0; i < 4; ++i)
        #pragma unroll
        for (int j = 0; j < 4; ++j) acc[i][j] = (f32x4){0.f, 0.f, 0.f, 0.f};

    const ushort* Ap = Ag + (size_t)(bm + sr) * KD + sc;
    const ushort* Bp = Bg + (size_t)(bn + sr) * KD + sc;

    uint4 ra[4], rb[4];
    #pragma unroll
    for (int e = 0; e < 4; ++e) {
        ra[e] = *(const uint4*)(Ap + (size_t)e * 32 * KD);
        rb[e] = *(const uint4*)(Bp + (size_t)e * 32 * KD);
    }

    for (int k0 = 0; k0 < KD; k0 += 64) {
        __syncthreads();
        #pragma unroll
        for (int e = 0; e < 4; ++e) {
            *(uint4*)&As[sr + e * 32][sc] = ra[e];
            *(uint4*)&Bs[sr + e * 32][sc] = rb[e];
        }
        __syncthreads();
        if (k0 + 64 < KD) {
            #pragma unroll
            for (int e = 0; e < 4; ++e) {
                ra[e] = *(const uint4*)(Ap + (size_t)e * 32 * KD + k0 + 64);
                rb[e] = *(const uint4*)(Bp + (size_t)e * 32 * KD + k0 + 64);
            }
        }
        #pragma unroll
        for (int ks = 0; ks < 2; ++ks) {
            short8 af[4], bfr[4];
            #pragma unroll
            for (int i = 0; i < 4; ++i)
                af[i] = *(const short8*)&As[wm + i * 16 + lr][ks * 32 + lk * 8];
            #pragma unroll
            for (int j = 0; j < 4; ++j)
                bfr[j] = *(const short8*)&Bs[wn + j * 16 + lr][ks * 32 + lk * 8];
            #pragma unroll
            for (int i = 0; i < 4; ++i)
                #pragma unroll
                for (int j = 0; j < 4; ++j)
                    acc[i][j] = __builtin_amdgcn_mfma_f32_16x16x32_bf16(
                        af[i], bfr[j], acc[i][j], 0, 0, 0);
        }
    }

    #pragma unroll
    for (int i = 0; i < 4; ++i) {
        #pragma unroll
        for (int j = 0; j < 4; ++j) {
            int col = bn + wn + j * 16 + lr;
            float bv = bias[col];
            #pragma unroll
            for (int r = 0; r < 4; ++r) {
                int row = bm + wm + i * 16 + lk * 4 + r;
                Cm[(size_t)row * NN + col] = acc[i][j][r] + bv;
            }
        }
    }
}

// ---------------------------------------------------------------------------
// FUSED kernel 1: per (b,h): Wh1 tile via MFMA -> LDS -> attention-1 ->
// c1 bf16 [b*T+t][h*64+c].  Eliminates the wh1m fp32 intermediate.
// ---------------------------------------------------------------------------
__global__ __launch_bounds__(256) void fused1_kernel(
    const ushort* __restrict__ xbf,   // [B*T][256] bf16
    const ushort* __restrict__ w1t,   // [H*64][256] bf16
    const float* __restrict__ b1,     // [4096]
    const float* __restrict__ a1s, const float* __restrict__ a1d,
    const float* __restrict__ a1b,
    ushort* __restrict__ c1)
{
    int blk = blockIdx.x; int b = blk >> 6, h = blk & 63;
    __shared__ ushort As[128][72];
    __shared__ ushort Bs[64][72];
    __shared__ float whs[128][65];
    __shared__ alignas(16) float pT[4][128][4];
    __shared__ float ss[128], ddv[128];

    int tid = threadIdx.x;
    int wave = tid >> 6, lane = tid & 63;
    int wm = (wave >> 1) * 64, wn = (wave & 1) * 32;
    int lr = lane & 15, lk = lane >> 4;
    int sr = tid >> 3, sc = (tid & 7) * 8;

    f32x4 acc[4][2];
    #pragma unroll
    for (int i = 0; i < 4; ++i)
        #pragma unroll
        for (int j = 0; j < 2; ++j) acc[i][j] = (f32x4){0.f, 0.f, 0.f, 0.f};

    const ushort* Ap = xbf + (size_t)(b * T + sr) * D + sc;
    const ushort* Bp = w1t + (size_t)(h * 64 + sr) * D + sc;

    uint4 ra[4], rb[2];
    #pragma unroll
    for (int e = 0; e < 4; ++e) ra[e] = *(const uint4*)(Ap + (size_t)e * 32 * D);
    #pragma unroll
    for (int e = 0; e < 2; ++e) rb[e] = *(const uint4*)(Bp + (size_t)e * 32 * D);

    for (int k0 = 0; k0 < D; k0 += 64) {
        __syncthreads();
        #pragma unroll
        for (int e = 0; e < 4; ++e) *(uint4*)&As[sr + e * 32][sc] = ra[e];
        if (sr < 32) {
            #pragma unroll
            for (int e = 0; e < 2; ++e) *(uint4*)&Bs[sr + e * 32][sc] = rb[e];
        }
        __syncthreads();
        if (k0 + 64 < D) {
            #pragma unroll
            for (int e = 0; e < 4; ++e)
                ra[e] = *(const uint4*)(Ap + (size_t)e * 32 * D + k0 + 64);
            #pragma unroll
            for (int e = 0; e < 2; ++e)
                rb[e] = *(const uint4*)(Bp + (size_t)e * 32 * D + k0 + 64);
        }
        #pragma unroll
        for (int ks = 0; ks < 2; ++ks) {
            short8 af[4], bfr[2];
            #pragma unroll
            for (int i = 0; i < 4; ++i)
                af[i] = *(const short8*)&As[wm + i * 16 + lr][ks * 32 + lk * 8];
            #pragma unroll
            for (int j = 0; j < 2; ++j)
                bfr[j] = *(const short8*)&Bs[wn + j * 16 + lr][ks * 32 + lk * 8];
            #pragma unroll
            for (int i = 0; i < 4; ++i)
                #pragma unroll
                for (int j = 0; j < 2; ++j)
                    acc[i][j] = __builtin_amdgcn_mfma_f32_16x16x32_bf16(
                        af[i], bfr[j], acc[i][j], 0, 0, 0);
        }
    }

    // epilogue: Wh1 tile -> whs (+bias)
    #pragma unroll
    for (int j = 0; j < 2; ++j) {
        int col = wn + j * 16 + lr;
        float bv = b1[h * C1 + col];
        #pragma unroll
        for (int i = 0; i < 4; ++i) {
            #pragma unroll
            for (int r = 0; r < 4; ++r)
                whs[wm + i * 16 + lk * 4 + r][col] = acc[i][j][r] + bv;
        }
    }
    __syncthreads();

    // ---- attention (verified attn1 body) ----
    if (tid < 128) {
        float s = a1b[h], dv = 0.f;
        #pragma unroll
        for (int c = 0; c < 64; ++c) {
            float v = whs[tid][c];
            s  = fmaf(v, a1s[h * C1 + c], s);
            dv = fmaf(v, a1d[h * C1 + c], dv);
        }
        ss[tid] = s; ddv[tid] = dv;
    }
    __syncthreads();

    int w = wave;
    float dj0 = ddv[lane], dj1 = ddv[lane + 64];
    for (int q = 0; q < 8; ++q) {
        for (int r = 0; r < 4; ++r) {
            int i = w * 32 + q * 4 + r;
            float si = ss[i];
            float e0 = si + dj0; e0 = e0 >= 0.f ? e0 : ALPHA * e0;
            float e1 = si + dj1; e1 = e1 >= 0.f ? e1 : ALPHA * e1;
            float m = fmaxf(e0, e1);
            for (int msk = 1; msk < 64; msk <<= 1) m = fmaxf(m, __shfl_xor(m, msk));
            float p0 = __expf(e0 - m), p1 = __expf(e1 - m);
            float sum = p0 + p1;
            for (int msk = 1; msk < 64; msk <<= 1) sum += __shfl_xor(sum, msk);
            float inv = 1.0f / sum;
            pT[w][lane][r] = p0 * inv; pT[w][lane + 64][r] = p1 * inv;
        }
        float a0 = 0, a1 = 0, a2 = 0, a3 = 0;
        for (int j = 0; j < 128; ++j) {
            float4 pv = *(const float4*)&pT[w][j][0];
            float wj = whs[j][lane];
            a0 = fmaf(pv.x, wj, a0); a1 = fmaf(pv.y, wj, a1);
            a2 = fmaf(pv.z, wj, a2); a3 = fmaf(pv.w, wj, a3);
        }
        int i0 = w * 32 + q * 4;
        float vals[4] = {a0, a1, a2, a3};
        #pragma unroll
        for (int r = 0; r < 4; ++r) {
            float v = vals[r]; v = v > 0.f ? v : 0.f;
            v = 1.0f / (1.0f + __expf(-v));
            c1[((size_t)(b * T + i0 + r)) * K2 + h * C1 + lane] = f2bf(v);
        }
    }
}

// ---------------------------------------------------------------------------
// Prep kernels
// ---------------------------------------------------------------------------
__global__ __launch_bounds__(256) void xbf_kernel(
    const float* __restrict__ x, ushort* __restrict__ xbf)
{
    int i = blockIdx.x * 256 + threadIdx.x;
    float4 v = *(const float4*)&x[(size_t)i * 4];
    union { ushort u[4]; uint2 p; } o;
    o.u[0] = f2bf(v.x); o.u[1] = f2bf(v.y);
    o.u[2] = f2bf(v.z); o.u[3] = f2bf(v.w);
    *(uint2*)&xbf[(size_t)i * 4] = o.p;
}

// W1[h,d,c] fp32 -> w1t[h*64+c][d] bf16
__global__ __launch_bounds__(256) void w1t_kernel(
    const float* __restrict__ W1, ushort* __restrict__ w1t)
{
    int blk = blockIdx.x; int h = blk >> 2, d0 = (blk & 3) * 64;
    __shared__ float lw[64][65];
    int tid = threadIdx.x;
    for (int e = 0; e < 16; ++e) {
        int idx = e * 256 + tid; int dr = idx >> 6, c = idx & 63;
        lw[dr][c] = W1[((size_t)h * D + d0 + dr) * C1 + c];
    }
    __syncthreads();
    for (int e = 0; e < 16; ++e) {
        int idx = e * 256 + tid; int c = idx >> 6, dr = idx & 63;
        w1t[((size_t)(h * 64 + c)) * D + d0 + dr] = f2bf(lw[dr][c]);
    }
}

// W2[h,k,c] fp32 -> w2t[h*20+c][k] bf16
__global__ __launch_bounds__(256) void w2t_kernel(
    const float* __restrict__ W2, ushort* __restrict__ w2t)
{
    int blk = blockIdx.x; int h = blk >> 5, kb = blk & 31; int k0 = kb * 128;
    __shared__ float lw[128][21];
    int tid = threadIdx.x;
    const float* src = W2 + ((size_t)h * K2 + k0) * C2;
    for (int e = 0; e < 10; ++e) {
        int idx = e * 256 + tid; int k = idx / 20, c = idx - k * 20;
        lw[k][c] = src[idx];
    }
    __syncthreads();
    for (int e = 0; e < 10; ++e) {
        int idx = e * 256 + tid; int c = idx >> 7, k = idx & 127;
        w2t[((size_t)(h * 20 + c)) * K2 + k0 + k] = f2bf(lw[k][c]);
    }
}

// slw[k=1280][d=256] fp32 -> slwt[d][k] bf16
__global__ __launch_bounds__(256) void slwt_kernel(
    const float* __restrict__ slw, ushort* __restrict__ slwt)
{
    int blk = blockIdx.x; int kb = blk >> 2, d0 = (blk & 3) * 64; int k0 = kb * 64;
    __shared__ float lw[64][65];
    int tid = threadIdx.x;
    for (int e = 0; e < 16; ++e) {
        int idx = e * 256 + tid; int kr = idx >> 6, dc = idx & 63;
        lw[kr][dc] = slw[((size_t)(k0 + kr)) * D + d0 + dc];
    }
    __syncthreads();
    for (int e = 0; e < 16; ++e) {
        int idx = e * 256 + tid; int dr = idx >> 6, kc = idx & 63;
        slwt[((size_t)(d0 + dr)) * F2 + k0 + kc] = f2bf(lw[kc][dr]);
    }
}

// ---------------------------------------------------------------------------
// attention-2: reads wh2m[b*T+t][h*20+c] fp32; writes c2 bf16 same layout.
// ---------------------------------------------------------------------------
__global__ __launch_bounds__(256) void attn2_kernel(
    const float* __restrict__ wh2m, const float* __restrict__ a2s,
    const float* __restrict__ a2d, const float* __restrict__ a2b,
    ushort* __restrict__ c2)
{
    int blk = blockIdx.x; int b = blk >> 6, h = blk & 63;
    __shared__ float whs[128][33];
    __shared__ alignas(16) float pT[4][128][4];
    __shared__ float ss[128], ddv[128];
    int tid = threadIdx.x; int w = tid >> 6, lane = tid & 63;
    const float* src = wh2m + (size_t)b * T * F2 + h * C2;

    for (int e = 0; e < 10; ++e) {
        int idx = e * 256 + tid; int t = idx / 20, c = idx - t * 20;
        whs[t][c] = src[(size_t)t * F2 + c];
    }
    for (int e = 0; e < 7; ++e) {
        int idx = e * 256 + tid;
        if (idx < 1664) { int t = idx / 13, c = 20 + (idx - t * 13); whs[t][c] = 0.f; }
    }
    __syncthreads();
    if (tid < 128) {
        float s = a2b[h], dv = 0.f;
        #pragma unroll
        for (int c = 0; c < 20; ++c) {
            float v = whs[tid][c];
            s  = fmaf(v, a2s[h * C2 + c], s);
            dv = fmaf(v, a2d[h * C2 + c], dv);
        }
        ss[tid] = s; ddv[tid] = dv;
    }
    __syncthreads();

    float dj0 = ddv[lane], dj1 = ddv[lane + 64];
    int cc = lane & 31, jh = lane >> 5;
    for (int q = 0; q < 8; ++q) {
        for (int r = 0; r < 4; ++r) {
            int i = w * 32 + q * 4 + r;
            float si = ss[i];
            float e0 = si + dj0; e0 = e0 >= 0.f ? e0 : ALPHA * e0;
            float e1 = si + dj1; e1 = e1 >= 0.f ? e1 : ALPHA * e1;
            float m = fmaxf(e0, e1);
            for (int msk = 1; msk < 64; msk <<= 1) m = fmaxf(m, __shfl_xor(m, msk));
            float p0 = __expf(e0 - m), p1 = __expf(e1 - m);
            float sum = p0 + p1;
            for (int msk = 1; msk < 64; msk <<= 1) sum += __shfl_xor(sum, msk);
            float inv = 1.0f / sum;
            pT[w][lane][r] = p0 * inv; pT[w][lane + 64][r] = p1 * inv;
        }
        float a0 = 0, a1 = 0, a2 = 0, a3 = 0;
        for (int jj = 0; jj < 64; ++jj) {
            int j = jh * 64 + jj;
            float4 pv = *(const float4*)&pT[w][j][0];
            float wj = whs[j][cc];
            a0 = fmaf(pv.x, wj, a0); a1 = fmaf(pv.y, wj, a1);
            a2 = fmaf(pv.z, wj, a2); a3 = fmaf(pv.w, wj, a3);
        }
        a0 += __shfl_xor(a0, 32); a1 += __shfl_xor(a1, 32);
        a2 += __shfl_xor(a2, 32); a3 += __shfl_xor(a3, 32);
        if (jh == 0 && cc < 20) {
            int i0 = w * 32 + q * 4;
            float vals[4] = {a0, a1, a2, a3};
            #pragma unroll
            for (int r = 0; r < 4; ++r) {
                float v = vals[r]; v = v > 0.f ? v : 0.f;
                v = 1.0f / (1.0f + __expf(-v));
                c2[((size_t)(b * T + i0 + r)) * F2 + h * C2 + cc] = f2bf(v);
            }
        }
    }
}

// ---------------------------------------------------------------------------
// GAR: res[b,o,d] = sum_t c3[b,t,d]*gar_w[t,o] + gar_b[o]
// ---------------------------------------------------------------------------
__global__ __launch_bounds__(256) void gar_kernel(
    const float* __restrict__ c3, const float* __restrict__ garw,
    const float* __restrict__ garb, float* __restrict__ out)
{
    int blk = blockIdx.x; int b = blk >> 5, o = blk & 31;
    int dcol = threadIdx.x;
    float acc = garb[o];
    const float* cp = c3 + (size_t)b * T * D + dcol;
    for (int t = 0; t < T; ++t)
        acc = fmaf(cp[(size_t)t * D], garw[t * OUTW + o], acc);
    out[((size_t)b * OUTW + o) * D + dcol] = acc;
}

// ---------------------------------------------------------------------------
extern "C" void kernel_launch(void* const* d_in, const int* in_sizes, int n_in,
                              void* d_out, int out_size, void* d_ws, size_t ws_size,
                              hipStream_t stream) {
    const float* x    = (const float*)d_in[0];
    const float* W1   = (const float*)d_in[1];
    const float* b1   = (const float*)d_in[2];
    const float* a1s  = (const float*)d_in[3];
    const float* a1d  = (const float*)d_in[4];
    const float* a1b  = (const float*)d_in[5];
    const float* W2   = (const float*)d_in[6];
    const float* b2   = (const float*)d_in[7];
    const float* a2s  = (const float*)d_in[8];
    const float* a2d  = (const float*)d_in[9];
    const float* a2b  = (const float*)d_in[10];
    const float* slw  = (const float*)d_in[11];
    const float* slb  = (const float*)d_in[12];
    const float* garw = (const float*)d_in[13];
    const float* garb = (const float*)d_in[14];

    char* p = (char*)d_ws;
    float*  wh2m = (float*)p;               p += (size_t)2048 * 1280 * 4;  // 10.5 MB
    float*  c3   = (float*)p;               p += (size_t)2048 * 256  * 4;  //  2.1 MB
    ushort* xbf  = (ushort*)p;              p += (size_t)2048 * 256  * 2;  //  1.0 MB
    ushort* w1t  = (ushort*)p;              p += (size_t)4096 * 256  * 2;  //  2.1 MB
    ushort* c1bf = (ushort*)p;              p += (size_t)2048 * 4096 * 2;  // 16.8 MB
    ushort* w2t  = (ushort*)p;              p += (size_t)1280 * 4096 * 2;  // 10.5 MB
    ushort* c2bf = (ushort*)p;              p += (size_t)2048 * 1280 * 2;  //  5.2 MB
    ushort* slwt = (ushort*)p;              p += (size_t)256  * 1280 * 2;  //  0.7 MB

    xbf_kernel <<<512,  256, 0, stream>>>(x, xbf);
    w1t_kernel <<<256,  256, 0, stream>>>(W1, w1t);
    w2t_kernel <<<2048, 256, 0, stream>>>(W2, w2t);
    slwt_kernel<<<80,   256, 0, stream>>>(slw, slwt);

    fused1_kernel<<<B * H, 256, 0, stream>>>(xbf, w1t, b1, a1s, a1d, a1b, c1bf);
    gemm_bf16_kernel<4096, 10><<<160, 256, 0, stream>>>(c1bf, w2t, b2, wh2m);
    attn2_kernel<<<B * H, 256, 0, stream>>>(wh2m, a2s, a2d, a2b, c2bf);
    gemm_bf16_kernel<1280, 2><<<32, 256, 0, stream>>>(c2bf, slwt, slb, c3);
    gar_kernel<<<B * OUTW, 256, 0, stream>>>(c3, garw, garb, (float*)d_out);
}

// Round 6
// 333.929 us; speedup vs baseline: 1.2251x; 1.2251x over previous
//
#include <hip/hip_runtime.h>
#include <hip/hip_bf16.h>

#define B 16
#define T 128
#define D 256
#define H 64
#define C1 64
#define C2 20
#define K2 4096   // H*C1
#define F2 1280   // H*C2
#define OUTW 32
#define ALPHA 0.2f

typedef __attribute__((ext_vector_type(8))) short short8;
typedef __attribute__((ext_vector_type(4))) float f32x4;

static __device__ __forceinline__ ushort f2bf(float f) {
    __hip_bfloat16 h = __float2bfloat16(f);
    return *reinterpret_cast<ushort*>(&h);
}

// ---------------------------------------------------------------------------
// Split-K MFMA GEMM: Cp[kp][m][n] = sum_{k in part kp} A[m][k]*Bt[n][k]
// (bias applied in the reduce). 128x128 tile, BK=64, 4 waves, 16x16x32 bf16.
// Bijective XCD-chunk swizzle: consecutive bids round-robin XCDs, so
// (bid&7)*(TOTAL/8)+(bid>>3) gives each XCD one contiguous wg chunk
// (per-XCD working set ~4.5MB ≈ L2). Requires TOTAL%8==0.
// ---------------------------------------------------------------------------
template<int KD, int NBLK, int MBLK, int KSPLIT>
__global__ __launch_bounds__(256) void gemm_splitk_kernel(
    const ushort* __restrict__ Ag, const ushort* __restrict__ Bg,
    float* __restrict__ Cp)
{
    __shared__ ushort As[128][72];
    __shared__ ushort Bs[128][72];
    constexpr int NN = NBLK * 128;
    constexpr int MM = MBLK * 128;
    constexpr int NT = MBLK * NBLK;
    constexpr int TOTAL = NT * KSPLIT;
    constexpr int KDP = KD / KSPLIT;
    static_assert(TOTAL % 8 == 0, "swizzle needs multiple of 8 blocks");

    int tid = threadIdx.x;
    int bid = blockIdx.x;
    int wg = (bid & 7) * (TOTAL / 8) + (bid >> 3);
    int kp = wg / NT; int tile = wg - kp * NT;
    int bm = (tile / NBLK) * 128, bn = (tile % NBLK) * 128;

    int wave = tid >> 6, lane = tid & 63;
    int wm = (wave >> 1) * 64, wn = (wave & 1) * 64;
    int lr = lane & 15, lk = lane >> 4;
    int sr = tid >> 3, sc = (tid & 7) * 8;

    f32x4 acc[4][4];
    #pragma unroll
    for (int i = 0; i < 4; ++i)
        #pragma unroll
        for (int j = 0; j < 4; ++j) acc[i][j] = (f32x4){0.f, 0.f, 0.f, 0.f};

    const ushort* Ap = Ag + (size_t)(bm + sr) * KD + kp * KDP + sc;
    const ushort* Bp = Bg + (size_t)(bn + sr) * KD + kp * KDP + sc;

    uint4 ra[4], rb[4];
    #pragma unroll
    for (int e = 0; e < 4; ++e) {
        ra[e] = *(const uint4*)(Ap + (size_t)e * 32 * KD);
        rb[e] = *(const uint4*)(Bp + (size_t)e * 32 * KD);
    }

    for (int k0 = 0; k0 < KDP; k0 += 64) {
        __syncthreads();
        #pragma unroll
        for (int e = 0; e < 4; ++e) {
            *(uint4*)&As[sr + e * 32][sc] = ra[e];
            *(uint4*)&Bs[sr + e * 32][sc] = rb[e];
        }
        __syncthreads();
        if (k0 + 64 < KDP) {
            #pragma unroll
            for (int e = 0; e < 4; ++e) {
                ra[e] = *(const uint4*)(Ap + (size_t)e * 32 * KD + k0 + 64);
                rb[e] = *(const uint4*)(Bp + (size_t)e * 32 * KD + k0 + 64);
            }
        }
        #pragma unroll
        for (int ks = 0; ks < 2; ++ks) {
            short8 af[4], bfr[4];
            #pragma unroll
            for (int i = 0; i < 4; ++i)
                af[i] = *(const short8*)&As[wm + i * 16 + lr][ks * 32 + lk * 8];
            #pragma unroll
            for (int j = 0; j < 4; ++j)
                bfr[j] = *(const short8*)&Bs[wn + j * 16 + lr][ks * 32 + lk * 8];
            #pragma unroll
            for (int i = 0; i < 4; ++i)
                #pragma unroll
                for (int j = 0; j < 4; ++j)
                    acc[i][j] = __builtin_amdgcn_mfma_f32_16x16x32_bf16(
                        af[i], bfr[j], acc[i][j], 0, 0, 0);
        }
    }

    float* Cout = Cp + (size_t)kp * MM * NN;
    #pragma unroll
    for (int i = 0; i < 4; ++i) {
        #pragma unroll
        for (int j = 0; j < 4; ++j) {
            int col = bn + wn + j * 16 + lr;
            #pragma unroll
            for (int r = 0; r < 4; ++r) {
                int row = bm + wm + i * 16 + lk * 4 + r;
                Cout[(size_t)row * NN + col] = acc[i][j][r];
            }
        }
    }
}

// ---------------------------------------------------------------------------
// reduce P split-K partials + bias: out[i] = sum_p parts[p*MN+i] + bias[i%NN]
// ---------------------------------------------------------------------------
template<int P, int NN>
__global__ __launch_bounds__(256) void reduce_bias_kernel(
    const float* __restrict__ parts, const float* __restrict__ bias,
    float* __restrict__ out, int MN)
{
    size_t off = ((size_t)blockIdx.x * 256 + threadIdx.x) * 4;
    float4 s = *(const float4*)&parts[off];
    #pragma unroll
    for (int p = 1; p < P; ++p) {
        float4 v = *(const float4*)&parts[(size_t)p * MN + off];
        s.x += v.x; s.y += v.y; s.z += v.z; s.w += v.w;
    }
    float4 bv = *(const float4*)&bias[(int)(off % NN)];
    s.x += bv.x; s.y += bv.y; s.z += bv.z; s.w += bv.w;
    *(float4*)&out[off] = s;
}

// ---------------------------------------------------------------------------
// FUSED kernel 1: per (b,h): Wh1 tile via MFMA -> LDS -> attention-1 ->
// c1 bf16 [b*T+t][h*64+c].
// ---------------------------------------------------------------------------
__global__ __launch_bounds__(256) void fused1_kernel(
    const ushort* __restrict__ xbf,   // [B*T][256] bf16
    const ushort* __restrict__ w1t,   // [H*64][256] bf16
    const float* __restrict__ b1,     // [4096]
    const float* __restrict__ a1s, const float* __restrict__ a1d,
    const float* __restrict__ a1b,
    ushort* __restrict__ c1)
{
    int blk = blockIdx.x; int b = blk >> 6, h = blk & 63;
    __shared__ ushort As[128][72];
    __shared__ ushort Bs[64][72];
    __shared__ float whs[128][65];
    __shared__ alignas(16) float pT[4][128][4];
    __shared__ float ss[128], ddv[128];

    int tid = threadIdx.x;
    int wave = tid >> 6, lane = tid & 63;
    int wm = (wave >> 1) * 64, wn = (wave & 1) * 32;
    int lr = lane & 15, lk = lane >> 4;
    int sr = tid >> 3, sc = (tid & 7) * 8;

    f32x4 acc[4][2];
    #pragma unroll
    for (int i = 0; i < 4; ++i)
        #pragma unroll
        for (int j = 0; j < 2; ++j) acc[i][j] = (f32x4){0.f, 0.f, 0.f, 0.f};

    const ushort* Ap = xbf + (size_t)(b * T + sr) * D + sc;
    const ushort* Bp = w1t + (size_t)(h * 64 + sr) * D + sc;

    uint4 ra[4], rb[2];
    #pragma unroll
    for (int e = 0; e < 4; ++e) ra[e] = *(const uint4*)(Ap + (size_t)e * 32 * D);
    #pragma unroll
    for (int e = 0; e < 2; ++e) rb[e] = *(const uint4*)(Bp + (size_t)e * 32 * D);

    for (int k0 = 0; k0 < D; k0 += 64) {
        __syncthreads();
        #pragma unroll
        for (int e = 0; e < 4; ++e) *(uint4*)&As[sr + e * 32][sc] = ra[e];
        if (sr < 32) {
            #pragma unroll
            for (int e = 0; e < 2; ++e) *(uint4*)&Bs[sr + e * 32][sc] = rb[e];
        }
        __syncthreads();
        if (k0 + 64 < D) {
            #pragma unroll
            for (int e = 0; e < 4; ++e)
                ra[e] = *(const uint4*)(Ap + (size_t)e * 32 * D + k0 + 64);
            #pragma unroll
            for (int e = 0; e < 2; ++e)
                rb[e] = *(const uint4*)(Bp + (size_t)e * 32 * D + k0 + 64);
        }
        #pragma unroll
        for (int ks = 0; ks < 2; ++ks) {
            short8 af[4], bfr[2];
            #pragma unroll
            for (int i = 0; i < 4; ++i)
                af[i] = *(const short8*)&As[wm + i * 16 + lr][ks * 32 + lk * 8];
            #pragma unroll
            for (int j = 0; j < 2; ++j)
                bfr[j] = *(const short8*)&Bs[wn + j * 16 + lr][ks * 32 + lk * 8];
            #pragma unroll
            for (int i = 0; i < 4; ++i)
                #pragma unroll
                for (int j = 0; j < 2; ++j)
                    acc[i][j] = __builtin_amdgcn_mfma_f32_16x16x32_bf16(
                        af[i], bfr[j], acc[i][j], 0, 0, 0);
        }
    }

    #pragma unroll
    for (int j = 0; j < 2; ++j) {
        int col = wn + j * 16 + lr;
        float bv = b1[h * C1 + col];
        #pragma unroll
        for (int i = 0; i < 4; ++i) {
            #pragma unroll
            for (int r = 0; r < 4; ++r)
                whs[wm + i * 16 + lk * 4 + r][col] = acc[i][j][r] + bv;
        }
    }
    __syncthreads();

    if (tid < 128) {
        float s = a1b[h], dv = 0.f;
        #pragma unroll
        for (int c = 0; c < 64; ++c) {
            float v = whs[tid][c];
            s  = fmaf(v, a1s[h * C1 + c], s);
            dv = fmaf(v, a1d[h * C1 + c], dv);
        }
        ss[tid] = s; ddv[tid] = dv;
    }
    __syncthreads();

    int w = wave;
    float dj0 = ddv[lane], dj1 = ddv[lane + 64];
    for (int q = 0; q < 8; ++q) {
        for (int r = 0; r < 4; ++r) {
            int i = w * 32 + q * 4 + r;
            float si = ss[i];
            float e0 = si + dj0; e0 = e0 >= 0.f ? e0 : ALPHA * e0;
            float e1 = si + dj1; e1 = e1 >= 0.f ? e1 : ALPHA * e1;
            float m = fmaxf(e0, e1);
            for (int msk = 1; msk < 64; msk <<= 1) m = fmaxf(m, __shfl_xor(m, msk));
            float p0 = __expf(e0 - m), p1 = __expf(e1 - m);
            float sum = p0 + p1;
            for (int msk = 1; msk < 64; msk <<= 1) sum += __shfl_xor(sum, msk);
            float inv = 1.0f / sum;
            pT[w][lane][r] = p0 * inv; pT[w][lane + 64][r] = p1 * inv;
        }
        float a0 = 0, a1 = 0, a2 = 0, a3 = 0;
        for (int j = 0; j < 128; ++j) {
            float4 pv = *(const float4*)&pT[w][j][0];
            float wj = whs[j][lane];
            a0 = fmaf(pv.x, wj, a0); a1 = fmaf(pv.y, wj, a1);
            a2 = fmaf(pv.z, wj, a2); a3 = fmaf(pv.w, wj, a3);
        }
        int i0 = w * 32 + q * 4;
        float vals[4] = {a0, a1, a2, a3};
        #pragma unroll
        for (int r = 0; r < 4; ++r) {
            float v = vals[r]; v = v > 0.f ? v : 0.f;
            v = 1.0f / (1.0f + __expf(-v));
            c1[((size_t)(b * T + i0 + r)) * K2 + h * C1 + lane] = f2bf(v);
        }
    }
}

// ---------------------------------------------------------------------------
// Prep kernels
// ---------------------------------------------------------------------------
__global__ __launch_bounds__(256) void xbf_kernel(
    const float* __restrict__ x, ushort* __restrict__ xbf)
{
    int i = blockIdx.x * 256 + threadIdx.x;
    float4 v = *(const float4*)&x[(size_t)i * 4];
    union { ushort u[4]; uint2 p; } o;
    o.u[0] = f2bf(v.x); o.u[1] = f2bf(v.y);
    o.u[2] = f2bf(v.z); o.u[3] = f2bf(v.w);
    *(uint2*)&xbf[(size_t)i * 4] = o.p;
}

// W1[h,d,c] fp32 -> w1t[h*64+c][d] bf16
__global__ __launch_bounds__(256) void w1t_kernel(
    const float* __restrict__ W1, ushort* __restrict__ w1t)
{
    int blk = blockIdx.x; int h = blk >> 2, d0 = (blk & 3) * 64;
    __shared__ float lw[64][65];
    int tid = threadIdx.x;
    for (int e = 0; e < 16; ++e) {
        int idx = e * 256 + tid; int dr = idx >> 6, c = idx & 63;
        lw[dr][c] = W1[((size_t)h * D + d0 + dr) * C1 + c];
    }
    __syncthreads();
    for (int e = 0; e < 16; ++e) {
        int idx = e * 256 + tid; int c = idx >> 6, dr = idx & 63;
        w1t[((size_t)(h * 64 + c)) * D + d0 + dr] = f2bf(lw[dr][c]);
    }
}

// W2[h,k,c] fp32 -> w2t[h*20+c][k] bf16
__global__ __launch_bounds__(256) void w2t_kernel(
    const float* __restrict__ W2, ushort* __restrict__ w2t)
{
    int blk = blockIdx.x; int h = blk >> 5, kb = blk & 31; int k0 = kb * 128;
    __shared__ float lw[128][21];
    int tid = threadIdx.x;
    const float* src = W2 + ((size_t)h * K2 + k0) * C2;
    for (int e = 0; e < 10; ++e) {
        int idx = e * 256 + tid; int k = idx / 20, c = idx - k * 20;
        lw[k][c] = src[idx];
    }
    __syncthreads();
    for (int e = 0; e < 10; ++e) {
        int idx = e * 256 + tid; int c = idx >> 7, k = idx & 127;
        w2t[((size_t)(h * 20 + c)) * K2 + k0 + k] = f2bf(lw[k][c]);
    }
}

// slw[k=1280][d=256] fp32 -> slwt[d][k] bf16
__global__ __launch_bounds__(256) void slwt_kernel(
    const float* __restrict__ slw, ushort* __restrict__ slwt)
{
    int blk = blockIdx.x; int kb = blk >> 2, d0 = (blk & 3) * 64; int k0 = kb * 64;
    __shared__ float lw[64][65];
    int tid = threadIdx.x;
    for (int e = 0; e < 16; ++e) {
        int idx = e * 256 + tid; int kr = idx >> 6, dc = idx & 63;
        lw[kr][dc] = slw[((size_t)(k0 + kr)) * D + d0 + dc];
    }
    __syncthreads();
    for (int e = 0; e < 16; ++e) {
        int idx = e * 256 + tid; int dr = idx >> 6, kc = idx & 63;
        slwt[((size_t)(d0 + dr)) * F2 + k0 + kc] = f2bf(lw[kc][dr]);
    }
}

// ---------------------------------------------------------------------------
// attention-2: reads wh2m[b*T+t][h*20+c] fp32; writes c2 bf16 same layout.
// ---------------------------------------------------------------------------
__global__ __launch_bounds__(256) void attn2_kernel(
    const float* __restrict__ wh2m, const float* __restrict__ a2s,
    const float* __restrict__ a2d, const float* __restrict__ a2b,
    ushort* __restrict__ c2)
{
    int blk = blockIdx.x; int b = blk >> 6, h = blk & 63;
    __shared__ float whs[128][33];
    __shared__ alignas(16) float pT[4][128][4];
    __shared__ float ss[128], ddv[128];
    int tid = threadIdx.x; int w = tid >> 6, lane = tid & 63;
    const float* src = wh2m + (size_t)b * T * F2 + h * C2;

    for (int e = 0; e < 10; ++e) {
        int idx = e * 256 + tid; int t = idx / 20, c = idx - t * 20;
        whs[t][c] = src[(size_t)t * F2 + c];
    }
    for (int e = 0; e < 7; ++e) {
        int idx = e * 256 + tid;
        if (idx < 1664) { int t = idx / 13, c = 20 + (idx - t * 13); whs[t][c] = 0.f; }
    }
    __syncthreads();
    if (tid < 128) {
        float s = a2b[h], dv = 0.f;
        #pragma unroll
        for (int c = 0; c < 20; ++c) {
            float v = whs[tid][c];
            s  = fmaf(v, a2s[h * C2 + c], s);
            dv = fmaf(v, a2d[h * C2 + c], dv);
        }
        ss[tid] = s; ddv[tid] = dv;
    }
    __syncthreads();

    float dj0 = ddv[lane], dj1 = ddv[lane + 64];
    int cc = lane & 31, jh = lane >> 5;
    for (int q = 0; q < 8; ++q) {
        for (int r = 0; r < 4; ++r) {
            int i = w * 32 + q * 4 + r;
            float si = ss[i];
            float e0 = si + dj0; e0 = e0 >= 0.f ? e0 : ALPHA * e0;
            float e1 = si + dj1; e1 = e1 >= 0.f ? e1 : ALPHA * e1;
            float m = fmaxf(e0, e1);
            for (int msk = 1; msk < 64; msk <<= 1) m = fmaxf(m, __shfl_xor(m, msk));
            float p0 = __expf(e0 - m), p1 = __expf(e1 - m);
            float sum = p0 + p1;
            for (int msk = 1; msk < 64; msk <<= 1) sum += __shfl_xor(sum, msk);
            float inv = 1.0f / sum;
            pT[w][lane][r] = p0 * inv; pT[w][lane + 64][r] = p1 * inv;
        }
        float a0 = 0, a1 = 0, a2 = 0, a3 = 0;
        for (int jj = 0; jj < 64; ++jj) {
            int j = jh * 64 + jj;
            float4 pv = *(const float4*)&pT[w][j][0];
            float wj = whs[j][cc];
            a0 = fmaf(pv.x, wj, a0); a1 = fmaf(pv.y, wj, a1);
            a2 = fmaf(pv.z, wj, a2); a3 = fmaf(pv.w, wj, a3);
        }
        a0 += __shfl_xor(a0, 32); a1 += __shfl_xor(a1, 32);
        a2 += __shfl_xor(a2, 32); a3 += __shfl_xor(a3, 32);
        if (jh == 0 && cc < 20) {
            int i0 = w * 32 + q * 4;
            float vals[4] = {a0, a1, a2, a3};
            #pragma unroll
            for (int r = 0; r < 4; ++r) {
                float v = vals[r]; v = v > 0.f ? v : 0.f;
                v = 1.0f / (1.0f + __expf(-v));
                c2[((size_t)(b * T + i0 + r)) * F2 + h * C2 + cc] = f2bf(v);
            }
        }
    }
}

// ---------------------------------------------------------------------------
// GAR: res[b,o,d] = sum_t c3[b,t,d]*gar_w[t,o] + gar_b[o]
// ---------------------------------------------------------------------------
__global__ __launch_bounds__(256) void gar_kernel(
    const float* __restrict__ c3, const float* __restrict__ garw,
    const float* __restrict__ garb, float* __restrict__ out)
{
    int blk = blockIdx.x; int b = blk >> 5, o = blk & 31;
    int dcol = threadIdx.x;
    float acc = garb[o];
    const float* cp = c3 + (size_t)b * T * D + dcol;
    for (int t = 0; t < T; ++t)
        acc = fmaf(cp[(size_t)t * D], garw[t * OUTW + o], acc);
    out[((size_t)b * OUTW + o) * D + dcol] = acc;
}

// ---------------------------------------------------------------------------
extern "C" void kernel_launch(void* const* d_in, const int* in_sizes, int n_in,
                              void* d_out, int out_size, void* d_ws, size_t ws_size,
                              hipStream_t stream) {
    const float* x    = (const float*)d_in[0];
    const float* W1   = (const float*)d_in[1];
    const float* b1   = (const float*)d_in[2];
    const float* a1s  = (const float*)d_in[3];
    const float* a1d  = (const float*)d_in[4];
    const float* a1b  = (const float*)d_in[5];
    const float* W2   = (const float*)d_in[6];
    const float* b2   = (const float*)d_in[7];
    const float* a2s  = (const float*)d_in[8];
    const float* a2d  = (const float*)d_in[9];
    const float* a2b  = (const float*)d_in[10];
    const float* slw  = (const float*)d_in[11];
    const float* slb  = (const float*)d_in[12];
    const float* garw = (const float*)d_in[13];
    const float* garb = (const float*)d_in[14];

    char* p = (char*)d_ws;
    float*  wh2m = (float*)p;   p += (size_t)2048 * 1280 * 4;   // 10.5 MB
    float*  c3   = (float*)p;   p += (size_t)2048 * 256  * 4;   //  2.1 MB
    ushort* xbf  = (ushort*)p;  p += (size_t)2048 * 256  * 2;   //  1.0 MB
    ushort* w1t  = (ushort*)p;  p += (size_t)4096 * 256  * 2;   //  2.1 MB
    ushort* c1bf = (ushort*)p;  p += (size_t)2048 * 4096 * 2;   // 16.8 MB
    ushort* w2t  = (ushort*)p;  p += (size_t)1280 * 4096 * 2;   // 10.5 MB
    ushort* c2bf = (ushort*)p;  p += (size_t)2048 * 1280 * 2;   //  5.2 MB
    ushort* slwt = (ushort*)p;  p += (size_t)256  * 1280 * 2;   //  0.7 MB
    float*  wh2p = (float*)p;   p += (size_t)4 * 2048 * 1280 * 4; // 42 MB
    // c3p (4 * 2048*256 fp32 = 8.4 MB) aliases c1bf (dead after gemm2 reads it)
    float*  c3p  = (float*)c1bf;

    xbf_kernel <<<512,  256, 0, stream>>>(x, xbf);
    w1t_kernel <<<256,  256, 0, stream>>>(W1, w1t);
    w2t_kernel <<<2048, 256, 0, stream>>>(W2, w2t);
    slwt_kernel<<<80,   256, 0, stream>>>(slw, slwt);

    fused1_kernel<<<B * H, 256, 0, stream>>>(xbf, w1t, b1, a1s, a1d, a1b, c1bf);

    gemm_splitk_kernel<4096, 10, 16, 4><<<640, 256, 0, stream>>>(c1bf, w2t, wh2p);
    reduce_bias_kernel<4, 1280><<<2560, 256, 0, stream>>>(wh2p, b2, wh2m,
                                                          2048 * 1280);
    attn2_kernel<<<B * H, 256, 0, stream>>>(wh2m, a2s, a2d, a2b, c2bf);

    gemm_splitk_kernel<1280, 2, 16, 4><<<128, 256, 0, stream>>>(c2bf, slwt, c3p);
    reduce_bias_kernel<4, 256><<<512, 256, 0, stream>>>(c3p, slb, c3, 2048 * 256);

    gar_kernel<<<B * OUTW, 256, 0, stream>>>(c3, garw, garb, (float*)d_out);
}

// Round 7
// 255.782 us; speedup vs baseline: 1.5994x; 1.3055x over previous
//
#include <hip/hip_runtime.h>
#include <hip/hip_bf16.h>

#define B 16
#define T 128
#define D 256
#define H 64
#define C1 64
#define C2 20
#define K2 4096   // H*C1
#define F2 1280   // H*C2
#define OUTW 32
#define ALPHA 0.2f

typedef __attribute__((ext_vector_type(8))) short short8;
typedef __attribute__((ext_vector_type(4))) float f32x4;

static __device__ __forceinline__ ushort f2bf(float f) {
    __hip_bfloat16 h = __float2bfloat16(f);
    return *reinterpret_cast<ushort*>(&h);
}
static __device__ __forceinline__ float bf2f(ushort u) {
    return __uint_as_float(((unsigned int)u) << 16);
}

// ---------------------------------------------------------------------------
// Split-K MFMA GEMM (verified round 6): Cp[kp][m][n] = partial sums.
// ---------------------------------------------------------------------------
template<int KD, int NBLK, int MBLK, int KSPLIT>
__global__ __launch_bounds__(256) void gemm_splitk_kernel(
    const ushort* __restrict__ Ag, const ushort* __restrict__ Bg,
    float* __restrict__ Cp)
{
    __shared__ ushort As[128][72];
    __shared__ ushort Bs[128][72];
    constexpr int NN = NBLK * 128;
    constexpr int MM = MBLK * 128;
    constexpr int NT = MBLK * NBLK;
    constexpr int TOTAL = NT * KSPLIT;
    constexpr int KDP = KD / KSPLIT;
    static_assert(TOTAL % 8 == 0, "swizzle needs multiple of 8 blocks");

    int tid = threadIdx.x;
    int bid = blockIdx.x;
    int wg = (bid & 7) * (TOTAL / 8) + (bid >> 3);
    int kp = wg / NT; int tile = wg - kp * NT;
    int bm = (tile / NBLK) * 128, bn = (tile % NBLK) * 128;

    int wave = tid >> 6, lane = tid & 63;
    int wm = (wave >> 1) * 64, wn = (wave & 1) * 64;
    int lr = lane & 15, lk = lane >> 4;
    int sr = tid >> 3, sc = (tid & 7) * 8;

    f32x4 acc[4][4];
    #pragma unroll
    for (int i = 0; i < 4; ++i)
        #pragma unroll
        for (int j = 0; j < 4; ++j) acc[i][j] = (f32x4){0.f, 0.f, 0.f, 0.f};

    const ushort* Ap = Ag + (size_t)(bm + sr) * KD + kp * KDP + sc;
    const ushort* Bp = Bg + (size_t)(bn + sr) * KD + kp * KDP + sc;

    uint4 ra[4], rb[4];
    #pragma unroll
    for (int e = 0; e < 4; ++e) {
        ra[e] = *(const uint4*)(Ap + (size_t)e * 32 * KD);
        rb[e] = *(const uint4*)(Bp + (size_t)e * 32 * KD);
    }

    for (int k0 = 0; k0 < KDP; k0 += 64) {
        __syncthreads();
        #pragma unroll
        for (int e = 0; e < 4; ++e) {
            *(uint4*)&As[sr + e * 32][sc] = ra[e];
            *(uint4*)&Bs[sr + e * 32][sc] = rb[e];
        }
        __syncthreads();
        if (k0 + 64 < KDP) {
            #pragma unroll
            for (int e = 0; e < 4; ++e) {
                ra[e] = *(const uint4*)(Ap + (size_t)e * 32 * KD + k0 + 64);
                rb[e] = *(const uint4*)(Bp + (size_t)e * 32 * KD + k0 + 64);
            }
        }
        #pragma unroll
        for (int ks = 0; ks < 2; ++ks) {
            short8 af[4], bfr[4];
            #pragma unroll
            for (int i = 0; i < 4; ++i)
                af[i] = *(const short8*)&As[wm + i * 16 + lr][ks * 32 + lk * 8];
            #pragma unroll
            for (int j = 0; j < 4; ++j)
                bfr[j] = *(const short8*)&Bs[wn + j * 16 + lr][ks * 32 + lk * 8];
            #pragma unroll
            for (int i = 0; i < 4; ++i)
                #pragma unroll
                for (int j = 0; j < 4; ++j)
                    acc[i][j] = __builtin_amdgcn_mfma_f32_16x16x32_bf16(
                        af[i], bfr[j], acc[i][j], 0, 0, 0);
        }
    }

    float* Cout = Cp + (size_t)kp * MM * NN;
    #pragma unroll
    for (int i = 0; i < 4; ++i) {
        #pragma unroll
        for (int j = 0; j < 4; ++j) {
            int col = bn + wn + j * 16 + lr;
            #pragma unroll
            for (int r = 0; r < 4; ++r) {
                int row = bm + wm + i * 16 + lk * 4 + r;
                Cout[(size_t)row * NN + col] = acc[i][j][r];
            }
        }
    }
}

// ---------------------------------------------------------------------------
// reduce P split-K partials + bias
// ---------------------------------------------------------------------------
template<int P, int NN>
__global__ __launch_bounds__(256) void reduce_bias_kernel(
    const float* __restrict__ parts, const float* __restrict__ bias,
    float* __restrict__ out, int MN)
{
    size_t off = ((size_t)blockIdx.x * 256 + threadIdx.x) * 4;
    float4 s = *(const float4*)&parts[off];
    #pragma unroll
    for (int p = 1; p < P; ++p) {
        float4 v = *(const float4*)&parts[(size_t)p * MN + off];
        s.x += v.x; s.y += v.y; s.z += v.z; s.w += v.w;
    }
    float4 bv = *(const float4*)&bias[(int)(off % NN)];
    s.x += bv.x; s.y += bv.y; s.z += bv.z; s.w += bv.w;
    *(float4*)&out[off] = s;
}

// ---------------------------------------------------------------------------
// FUSED kernel 1 v2: per (b,h):
//  A) Wh1 = x @ W1^T via MFMA -> whT[c][t] bf16 in LDS (+bias)
//  B) scores: ss[t]=<Wh,a1s>+a1b, ddv[t]=<Wh,a1d>  (reads whT columns)
//  C) dmax = max_j ddv  (monotone leaky => row max m_i = leaky(ss_i+dmax));
//     P~[i][j] = exp(leaky(ss_i+ddv_j) - m_i) bf16 -> Pb (MFMA A layout);
//     row sums via one shfl_xor -> sinv.
//  D) out = (P~ @ Wh) * sinv, relu, sigmoid -> c1 bf16.
// LDS: union(staging, Pb) 34.8KB + whT 17.4KB + 1.5KB = 53.8KB -> 3 blk/CU.
// ---------------------------------------------------------------------------
#define AS_(r,c)  u.stag[(r) * 72 + (c)]
#define BS_(r,c)  u.stag[9216 + (r) * 72 + (c)]
#define PB_(r,c)  u.Pb[(r) * 136 + (c)]
#define WHT_(r,c) whT[(r) * 136 + (c)]

__global__ __launch_bounds__(256) void fused1_kernel(
    const ushort* __restrict__ xbf,   // [B*T][256] bf16
    const ushort* __restrict__ w1t,   // [H*64][256] bf16
    const float* __restrict__ b1,     // [4096] ([h][c] flat)
    const float* __restrict__ a1s, const float* __restrict__ a1d,
    const float* __restrict__ a1b,
    ushort* __restrict__ c1)
{
    int blk = blockIdx.x; int b = blk >> 6, h = blk & 63;
    __shared__ union {
        ushort stag[128 * 72 + 64 * 72];   // As[128][72] + Bs[64][72]
        ushort Pb[128 * 136];              // P~ tile (A-operand layout)
    } u;
    __shared__ ushort whT[64 * 136];       // Wh1^T: [c][t] (B-operand layout)
    __shared__ float ss[128], ddv[128], sinv[128];

    int tid = threadIdx.x;
    int wave = tid >> 6, lane = tid & 63;
    int wm = (wave >> 1) * 64, wn = (wave & 1) * 32;
    int lr = lane & 15, lk = lane >> 4;
    int sr = tid >> 3, sc = (tid & 7) * 8;

    // ---- phase A: Wh1 MFMA ----
    f32x4 acc[4][2];
    #pragma unroll
    for (int i = 0; i < 4; ++i)
        #pragma unroll
        for (int j = 0; j < 2; ++j) acc[i][j] = (f32x4){0.f, 0.f, 0.f, 0.f};

    const ushort* Ap = xbf + (size_t)(b * T + sr) * D + sc;
    const ushort* Bp = w1t + (size_t)(h * 64 + sr) * D + sc;

    uint4 ra[4], rb[2];
    #pragma unroll
    for (int e = 0; e < 4; ++e) ra[e] = *(const uint4*)(Ap + (size_t)e * 32 * D);
    #pragma unroll
    for (int e = 0; e < 2; ++e) rb[e] = *(const uint4*)(Bp + (size_t)e * 32 * D);

    for (int k0 = 0; k0 < D; k0 += 64) {
        __syncthreads();
        #pragma unroll
        for (int e = 0; e < 4; ++e) *(uint4*)&AS_(sr + e * 32, sc) = ra[e];
        if (sr < 32) {
            #pragma unroll
            for (int e = 0; e < 2; ++e) *(uint4*)&BS_(sr + e * 32, sc) = rb[e];
        }
        __syncthreads();
        if (k0 + 64 < D) {
            #pragma unroll
            for (int e = 0; e < 4; ++e)
                ra[e] = *(const uint4*)(Ap + (size_t)e * 32 * D + k0 + 64);
            #pragma unroll
            for (int e = 0; e < 2; ++e)
                rb[e] = *(const uint4*)(Bp + (size_t)e * 32 * D + k0 + 64);
        }
        #pragma unroll
        for (int ks = 0; ks < 2; ++ks) {
            short8 af[4], bfr[2];
            #pragma unroll
            for (int i = 0; i < 4; ++i)
                af[i] = *(const short8*)&AS_(wm + i * 16 + lr, ks * 32 + lk * 8);
            #pragma unroll
            for (int j = 0; j < 2; ++j)
                bfr[j] = *(const short8*)&BS_(wn + j * 16 + lr, ks * 32 + lk * 8);
            #pragma unroll
            for (int i = 0; i < 4; ++i)
                #pragma unroll
                for (int j = 0; j < 2; ++j)
                    acc[i][j] = __builtin_amdgcn_mfma_f32_16x16x32_bf16(
                        af[i], bfr[j], acc[i][j], 0, 0, 0);
        }
    }

    // epilogue: whT[c][t] = bf16(Wh + bias)   (4 bf16 packed per uint2)
    #pragma unroll
    for (int j = 0; j < 2; ++j) {
        int col = wn + j * 16 + lr;
        float bv = b1[h * C1 + col];
        #pragma unroll
        for (int i = 0; i < 4; ++i) {
            int t0 = wm + i * 16 + lk * 4;
            union { ushort q[4]; uint2 v; } pk;
            #pragma unroll
            for (int r = 0; r < 4; ++r) pk.q[r] = f2bf(acc[i][j][r] + bv);
            *(uint2*)&WHT_(col, t0) = pk.v;
        }
    }
    __syncthreads();

    // ---- phase B: scores ----
    {
        int t = tid & 127;
        bool isS = tid < 128;
        const float* av = (isS ? a1s : a1d) + h * C1;
        float s = isS ? a1b[h] : 0.f;
        #pragma unroll 8
        for (int c = 0; c < 64; ++c) s = fmaf(bf2f(WHT_(c, t)), av[c], s);
        if (isS) ss[t] = s; else ddv[t] = s;
    }
    __syncthreads();

    // ---- phase C: P~ + row sums ----
    {
        float dm = fmaxf(ddv[lane], ddv[lane + 64]);
        #pragma unroll
        for (int msk = 1; msk < 64; msk <<= 1) dm = fmaxf(dm, __shfl_xor(dm, msk));
        int i = tid >> 1, j0 = (tid & 1) * 64;
        float si = ss[i];
        float mx = si + dm; mx = mx >= 0.f ? mx : ALPHA * mx;
        float lsum = 0.f;
        #pragma unroll
        for (int g = 0; g < 8; ++g) {
            union { ushort q[8]; uint4 v; } pk;
            #pragma unroll
            for (int e = 0; e < 8; ++e) {
                float ee = si + ddv[j0 + g * 8 + e];
                ee = ee >= 0.f ? ee : ALPHA * ee;
                float pp = __expf(ee - mx);
                lsum += pp;
                pk.q[e] = f2bf(pp);
            }
            *(uint4*)&PB_(i, j0 + g * 8) = pk.v;
        }
        lsum += __shfl_xor(lsum, 1);
        if (!(tid & 1)) sinv[i] = 1.0f / lsum;
    }
    __syncthreads();

    // ---- phase D: out = P~ @ Wh  (A=Pb[128][128], Bt=whT[64][128]) ----
    f32x4 acc2[4][2];
    #pragma unroll
    for (int i = 0; i < 4; ++i)
        #pragma unroll
        for (int j = 0; j < 2; ++j) acc2[i][j] = (f32x4){0.f, 0.f, 0.f, 0.f};

    #pragma unroll
    for (int ks = 0; ks < 4; ++ks) {
        short8 af[4], bfr[2];
        #pragma unroll
        for (int i = 0; i < 4; ++i)
            af[i] = *(const short8*)&PB_(wm + i * 16 + lr, ks * 32 + lk * 8);
        #pragma unroll
        for (int j = 0; j < 2; ++j)
            bfr[j] = *(const short8*)&WHT_(wn + j * 16 + lr, ks * 32 + lk * 8);
        #pragma unroll
        for (int i = 0; i < 4; ++i)
            #pragma unroll
            for (int j = 0; j < 2; ++j)
                acc2[i][j] = __builtin_amdgcn_mfma_f32_16x16x32_bf16(
                    af[i], bfr[j], acc2[i][j], 0, 0, 0);
    }

    #pragma unroll
    for (int i = 0; i < 4; ++i) {
        #pragma unroll
        for (int r = 0; r < 4; ++r) {
            int row = wm + i * 16 + lk * 4 + r;
            float sv = sinv[row];
            #pragma unroll
            for (int j = 0; j < 2; ++j) {
                int col = wn + j * 16 + lr;
                float v = acc2[i][j][r] * sv;
                v = v > 0.f ? v : 0.f;
                v = 1.0f / (1.0f + __expf(-v));
                c1[((size_t)(b * T + row)) * K2 + h * C1 + col] = f2bf(v);
            }
        }
    }
}

// ---------------------------------------------------------------------------
// Prep kernels
// ---------------------------------------------------------------------------
__global__ __launch_bounds__(256) void xbf_kernel(
    const float* __restrict__ x, ushort* __restrict__ xbf)
{
    int i = blockIdx.x * 256 + threadIdx.x;
    float4 v = *(const float4*)&x[(size_t)i * 4];
    union { ushort u[4]; uint2 p; } o;
    o.u[0] = f2bf(v.x); o.u[1] = f2bf(v.y);
    o.u[2] = f2bf(v.z); o.u[3] = f2bf(v.w);
    *(uint2*)&xbf[(size_t)i * 4] = o.p;
}

// W1[h,d,c] fp32 -> w1t[h*64+c][d] bf16
__global__ __launch_bounds__(256) void w1t_kernel(
    const float* __restrict__ W1, ushort* __restrict__ w1t)
{
    int blk = blockIdx.x; int h = blk >> 2, d0 = (blk & 3) * 64;
    __shared__ float lw[64][65];
    int tid = threadIdx.x;
    for (int e = 0; e < 16; ++e) {
        int idx = e * 256 + tid; int dr = idx >> 6, c = idx & 63;
        lw[dr][c] = W1[((size_t)h * D + d0 + dr) * C1 + c];
    }
    __syncthreads();
    for (int e = 0; e < 16; ++e) {
        int idx = e * 256 + tid; int c = idx >> 6, dr = idx & 63;
        w1t[((size_t)(h * 64 + c)) * D + d0 + dr] = f2bf(lw[dr][c]);
    }
}

// W2[h,k,c] fp32 -> w2t[h*20+c][k] bf16
__global__ __launch_bounds__(256) void w2t_kernel(
    const float* __restrict__ W2, ushort* __restrict__ w2t)
{
    int blk = blockIdx.x; int h = blk >> 5, kb = blk & 31; int k0 = kb * 128;
    __shared__ float lw[128][21];
    int tid = threadIdx.x;
    const float* src = W2 + ((size_t)h * K2 + k0) * C2;
    for (int e = 0; e < 10; ++e) {
        int idx = e * 256 + tid; int k = idx / 20, c = idx - k * 20;
        lw[k][c] = src[idx];
    }
    __syncthreads();
    for (int e = 0; e < 10; ++e) {
        int idx = e * 256 + tid; int c = idx >> 7, k = idx & 127;
        w2t[((size_t)(h * 20 + c)) * K2 + k0 + k] = f2bf(lw[k][c]);
    }
}

// slw[k=1280][d=256] fp32 -> slwt[d][k] bf16
__global__ __launch_bounds__(256) void slwt_kernel(
    const float* __restrict__ slw, ushort* __restrict__ slwt)
{
    int blk = blockIdx.x; int kb = blk >> 2, d0 = (blk & 3) * 64; int k0 = kb * 64;
    __shared__ float lw[64][65];
    int tid = threadIdx.x;
    for (int e = 0; e < 16; ++e) {
        int idx = e * 256 + tid; int kr = idx >> 6, dc = idx & 63;
        lw[kr][dc] = slw[((size_t)(k0 + kr)) * D + d0 + dc];
    }
    __syncthreads();
    for (int e = 0; e < 16; ++e) {
        int idx = e * 256 + tid; int dr = idx >> 6, kc = idx & 63;
        slwt[((size_t)(d0 + dr)) * F2 + k0 + kc] = f2bf(lw[kc][dr]);
    }
}

// ---------------------------------------------------------------------------
// attention-2 (unchanged): reads wh2m fp32; writes c2 bf16.
// ---------------------------------------------------------------------------
__global__ __launch_bounds__(256) void attn2_kernel(
    const float* __restrict__ wh2m, const float* __restrict__ a2s,
    const float* __restrict__ a2d, const float* __restrict__ a2b,
    ushort* __restrict__ c2)
{
    int blk = blockIdx.x; int b = blk >> 6, h = blk & 63;
    __shared__ float whs[128][33];
    __shared__ alignas(16) float pT[4][128][4];
    __shared__ float ss[128], ddv[128];
    int tid = threadIdx.x; int w = tid >> 6, lane = tid & 63;
    const float* src = wh2m + (size_t)b * T * F2 + h * C2;

    for (int e = 0; e < 10; ++e) {
        int idx = e * 256 + tid; int t = idx / 20, c = idx - t * 20;
        whs[t][c] = src[(size_t)t * F2 + c];
    }
    for (int e = 0; e < 7; ++e) {
        int idx = e * 256 + tid;
        if (idx < 1664) { int t = idx / 13, c = 20 + (idx - t * 13); whs[t][c] = 0.f; }
    }
    __syncthreads();
    if (tid < 128) {
        float s = a2b[h], dv = 0.f;
        #pragma unroll
        for (int c = 0; c < 20; ++c) {
            float v = whs[tid][c];
            s  = fmaf(v, a2s[h * C2 + c], s);
            dv = fmaf(v, a2d[h * C2 + c], dv);
        }
        ss[tid] = s; ddv[tid] = dv;
    }
    __syncthreads();

    float dj0 = ddv[lane], dj1 = ddv[lane + 64];
    int cc = lane & 31, jh = lane >> 5;
    for (int q = 0; q < 8; ++q) {
        for (int r = 0; r < 4; ++r) {
            int i = w * 32 + q * 4 + r;
            float si = ss[i];
            float e0 = si + dj0; e0 = e0 >= 0.f ? e0 : ALPHA * e0;
            float e1 = si + dj1; e1 = e1 >= 0.f ? e1 : ALPHA * e1;
            float m = fmaxf(e0, e1);
            for (int msk = 1; msk < 64; msk <<= 1) m = fmaxf(m, __shfl_xor(m, msk));
            float p0 = __expf(e0 - m), p1 = __expf(e1 - m);
            float sum = p0 + p1;
            for (int msk = 1; msk < 64; msk <<= 1) sum += __shfl_xor(sum, msk);
            float inv = 1.0f / sum;
            pT[w][lane][r] = p0 * inv; pT[w][lane + 64][r] = p1 * inv;
        }
        float a0 = 0, a1 = 0, a2 = 0, a3 = 0;
        for (int jj = 0; jj < 64; ++jj) {
            int j = jh * 64 + jj;
            float4 pv = *(const float4*)&pT[w][j][0];
            float wj = whs[j][cc];
            a0 = fmaf(pv.x, wj, a0); a1 = fmaf(pv.y, wj, a1);
            a2 = fmaf(pv.z, wj, a2); a3 = fmaf(pv.w, wj, a3);
        }
        a0 += __shfl_xor(a0, 32); a1 += __shfl_xor(a1, 32);
        a2 += __shfl_xor(a2, 32); a3 += __shfl_xor(a3, 32);
        if (jh == 0 && cc < 20) {
            int i0 = w * 32 + q * 4;
            float vals[4] = {a0, a1, a2, a3};
            #pragma unroll
            for (int r = 0; r < 4; ++r) {
                float v = vals[r]; v = v > 0.f ? v : 0.f;
                v = 1.0f / (1.0f + __expf(-v));
                c2[((size_t)(b * T + i0 + r)) * F2 + h * C2 + cc] = f2bf(v);
            }
        }
    }
}

// ---------------------------------------------------------------------------
// GAR: res[b,o,d] = sum_t c3[b,t,d]*gar_w[t,o] + gar_b[o]
// ---------------------------------------------------------------------------
__global__ __launch_bounds__(256) void gar_kernel(
    const float* __restrict__ c3, const float* __restrict__ garw,
    const float* __restrict__ garb, float* __restrict__ out)
{
    int blk = blockIdx.x; int b = blk >> 5, o = blk & 31;
    int dcol = threadIdx.x;
    float acc = garb[o];
    const float* cp = c3 + (size_t)b * T * D + dcol;
    for (int t = 0; t < T; ++t)
        acc = fmaf(cp[(size_t)t * D], garw[t * OUTW + o], acc);
    out[((size_t)b * OUTW + o) * D + dcol] = acc;
}

// ---------------------------------------------------------------------------
extern "C" void kernel_launch(void* const* d_in, const int* in_sizes, int n_in,
                              void* d_out, int out_size, void* d_ws, size_t ws_size,
                              hipStream_t stream) {
    const float* x    = (const float*)d_in[0];
    const float* W1   = (const float*)d_in[1];
    const float* b1   = (const float*)d_in[2];
    const float* a1s  = (const float*)d_in[3];
    const float* a1d  = (const float*)d_in[4];
    const float* a1b  = (const float*)d_in[5];
    const float* W2   = (const float*)d_in[6];
    const float* b2   = (const float*)d_in[7];
    const float* a2s  = (const float*)d_in[8];
    const float* a2d  = (const float*)d_in[9];
    const float* a2b  = (const float*)d_in[10];
    const float* slw  = (const float*)d_in[11];
    const float* slb  = (const float*)d_in[12];
    const float* garw = (const float*)d_in[13];
    const float* garb = (const float*)d_in[14];

    char* p = (char*)d_ws;
    float*  wh2m = (float*)p;   p += (size_t)2048 * 1280 * 4;   // 10.5 MB
    float*  c3   = (float*)p;   p += (size_t)2048 * 256  * 4;   //  2.1 MB
    ushort* xbf  = (ushort*)p;  p += (size_t)2048 * 256  * 2;   //  1.0 MB
    ushort* w1t  = (ushort*)p;  p += (size_t)4096 * 256  * 2;   //  2.1 MB
    ushort* c1bf = (ushort*)p;  p += (size_t)2048 * 4096 * 2;   // 16.8 MB
    ushort* w2t  = (ushort*)p;  p += (size_t)1280 * 4096 * 2;   // 10.5 MB
    ushort* c2bf = (ushort*)p;  p += (size_t)2048 * 1280 * 2;   //  5.2 MB
    ushort* slwt = (ushort*)p;  p += (size_t)256  * 1280 * 2;   //  0.7 MB
    float*  wh2p = (float*)p;   p += (size_t)4 * 2048 * 1280 * 4; // 42 MB
    float*  c3p  = (float*)c1bf;   // aliases c1bf (dead after gemm2 reads it)

    xbf_kernel <<<512,  256, 0, stream>>>(x, xbf);
    w1t_kernel <<<256,  256, 0, stream>>>(W1, w1t);
    w2t_kernel <<<2048, 256, 0, stream>>>(W2, w2t);
    slwt_kernel<<<80,   256, 0, stream>>>(slw, slwt);

    fused1_kernel<<<B * H, 256, 0, stream>>>(xbf, w1t, b1, a1s, a1d, a1b, c1bf);

    gemm_splitk_kernel<4096, 10, 16, 4><<<640, 256, 0, stream>>>(c1bf, w2t, wh2p);
    reduce_bias_kernel<4, 1280><<<2560, 256, 0, stream>>>(wh2p, b2, wh2m,
                                                          2048 * 1280);
    attn2_kernel<<<B * H, 256, 0, stream>>>(wh2m, a2s, a2d, a2b, c2bf);

    gemm_splitk_kernel<1280, 2, 16, 4><<<128, 256, 0, stream>>>(c2bf, slwt, c3p);
    reduce_bias_kernel<4, 256><<<512, 256, 0, stream>>>(c3p, slb, c3, 2048 * 256);

    gar_kernel<<<B * OUTW, 256, 0, stream>>>(c3, garw, garb, (float*)d_out);
}

// Round 8
// 175.939 us; speedup vs baseline: 2.3252x; 1.4538x over previous
//
#include <hip/hip_runtime.h>
#include <hip/hip_bf16.h>

#define B 16
#define T 128
#define D 256
#define H 64
#define C1 64
#define C2 20
#define K2 4096   // H*C1
#define F2 1280   // H*C2
#define OUTW 32
#define ALPHA 0.2f

typedef __attribute__((ext_vector_type(8))) short short8;
typedef __attribute__((ext_vector_type(4))) float f32x4;

static __device__ __forceinline__ ushort f2bf(float f) {
    __hip_bfloat16 h = __float2bfloat16(f);
    return *reinterpret_cast<ushort*>(&h);
}
static __device__ __forceinline__ float bf2f(ushort u) {
    return __uint_as_float(((unsigned int)u) << 16);
}
// async global->LDS, 16B per lane; LDS dest is wave-uniform base + lane*16.
static __device__ __forceinline__ void gload16(const ushort* g, ushort* l) {
    __builtin_amdgcn_global_load_lds((const unsigned int*)g, (unsigned int*)l,
                                     16, 0, 0);
}

// ---------------------------------------------------------------------------
// Split-K MFMA GEMM v2 (m97-style): global_load_lds staging, linear LDS,
// bf16 partials. Cp[kp][m][n] = sum_{k in part kp} A[m][k]*Bt[n][k].
// 128x128 tile, BK=64, 4 waves, 16x16x32 bf16.
// XCD swizzle: with KSPLIT==8, each XCD owns one K-part (A-slice 2MB +
// B-slice 1.25MB fits its 4MB L2).
// ---------------------------------------------------------------------------
template<int KD, int NBLK, int MBLK, int KSPLIT>
__global__ __launch_bounds__(256) void gemm_splitk_kernel(
    const ushort* __restrict__ Ag, const ushort* __restrict__ Bg,
    ushort* __restrict__ Cp)
{
    __shared__ ushort As[128 * 64];
    __shared__ ushort Bs[128 * 64];
    constexpr int NN = NBLK * 128;
    constexpr int MM = MBLK * 128;
    constexpr int NT = MBLK * NBLK;
    constexpr int TOTAL = NT * KSPLIT;
    constexpr int KDP = KD / KSPLIT;
    static_assert(TOTAL % 8 == 0, "swizzle needs multiple of 8 blocks");

    int tid = threadIdx.x;
    int bid = blockIdx.x;
    int wg = (bid & 7) * (TOTAL / 8) + (bid >> 3);
    int kp = wg / NT; int tile = wg - kp * NT;
    int bm = (tile / NBLK) * 128, bn = (tile % NBLK) * 128;

    int wave = tid >> 6, lane = tid & 63;
    int wm = (wave >> 1) * 64, wn = (wave & 1) * 64;
    int lr = lane & 15, lk = lane >> 4;
    int srow = lane >> 3, scol = (lane & 7) * 8;   // lane's slot within a 1KB chunk

    f32x4 acc[4][4];
    #pragma unroll
    for (int i = 0; i < 4; ++i)
        #pragma unroll
        for (int j = 0; j < 4; ++j) acc[i][j] = (f32x4){0.f, 0.f, 0.f, 0.f};

    const ushort* ApB = Ag + (size_t)bm * KD + kp * KDP;
    const ushort* BpB = Bg + (size_t)bn * KD + kp * KDP;

    for (int k0 = 0; k0 < KDP; k0 += 64) {
        __syncthreads();                       // prev tile's ds_reads done
        #pragma unroll
        for (int e = 0; e < 4; ++e) {
            int c = e * 4 + wave;              // chunk 0..15 (8 rows x 64 cols)
            gload16(ApB + (size_t)(8 * c + srow) * KD + k0 + scol, &As[c * 512]);
            gload16(BpB + (size_t)(8 * c + srow) * KD + k0 + scol, &Bs[c * 512]);
        }
        __syncthreads();                       // drains vmcnt: tile ready
        #pragma unroll
        for (int ks = 0; ks < 2; ++ks) {
            short8 af[4], bfr[4];
            #pragma unroll
            for (int i = 0; i < 4; ++i)
                af[i] = *(const short8*)&As[(wm + i * 16 + lr) * 64 + ks * 32 + lk * 8];
            #pragma unroll
            for (int j = 0; j < 4; ++j)
                bfr[j] = *(const short8*)&Bs[(wn + j * 16 + lr) * 64 + ks * 32 + lk * 8];
            #pragma unroll
            for (int i = 0; i < 4; ++i)
                #pragma unroll
                for (int j = 0; j < 4; ++j)
                    acc[i][j] = __builtin_amdgcn_mfma_f32_16x16x32_bf16(
                        af[i], bfr[j], acc[i][j], 0, 0, 0);
        }
    }

    ushort* Cout = Cp + (size_t)kp * MM * NN;
    #pragma unroll
    for (int i = 0; i < 4; ++i) {
        #pragma unroll
        for (int j = 0; j < 4; ++j) {
            int col = bn + wn + j * 16 + lr;
            #pragma unroll
            for (int r = 0; r < 4; ++r) {
                int row = bm + wm + i * 16 + lk * 4 + r;
                Cout[(size_t)row * NN + col] = f2bf(acc[i][j][r]);
            }
        }
    }
}

// ---------------------------------------------------------------------------
// reduce P bf16 split-K partials + bias -> fp32 out. 4 elems/thread.
// ---------------------------------------------------------------------------
template<int P, int NN>
__global__ __launch_bounds__(256) void reduce_bias_kernel(
    const ushort* __restrict__ parts, const float* __restrict__ bias,
    float* __restrict__ out, int MN)
{
    size_t off = ((size_t)blockIdx.x * 256 + threadIdx.x) * 4;
    float s0 = 0.f, s1 = 0.f, s2 = 0.f, s3 = 0.f;
    #pragma unroll
    for (int p = 0; p < P; ++p) {
        uint2 v = *(const uint2*)&parts[(size_t)p * MN + off];
        s0 += bf2f((ushort)(v.x & 0xffff));
        s1 += bf2f((ushort)(v.x >> 16));
        s2 += bf2f((ushort)(v.y & 0xffff));
        s3 += bf2f((ushort)(v.y >> 16));
    }
    float4 bv = *(const float4*)&bias[(int)(off % NN)];
    float4 o; o.x = s0 + bv.x; o.y = s1 + bv.y; o.z = s2 + bv.z; o.w = s3 + bv.w;
    *(float4*)&out[off] = o;
}

// ---------------------------------------------------------------------------
// FUSED kernel 1 (verified round 7): Wh1 MFMA -> scores -> P~ -> PV MFMA.
// ---------------------------------------------------------------------------
#define AS_(r,c)  u.stag[(r) * 72 + (c)]
#define BS_(r,c)  u.stag[9216 + (r) * 72 + (c)]
#define PB_(r,c)  u.Pb[(r) * 136 + (c)]
#define WHT_(r,c) whT[(r) * 136 + (c)]

__global__ __launch_bounds__(256) void fused1_kernel(
    const ushort* __restrict__ xbf,   // [B*T][256] bf16
    const ushort* __restrict__ w1t,   // [H*64][256] bf16
    const float* __restrict__ b1,     // [4096] ([h][c] flat)
    const float* __restrict__ a1s, const float* __restrict__ a1d,
    const float* __restrict__ a1b,
    ushort* __restrict__ c1)
{
    int blk = blockIdx.x; int b = blk >> 6, h = blk & 63;
    __shared__ union {
        ushort stag[128 * 72 + 64 * 72];
        ushort Pb[128 * 136];
    } u;
    __shared__ ushort whT[64 * 136];
    __shared__ float ss[128], ddv[128], sinv[128];

    int tid = threadIdx.x;
    int wave = tid >> 6, lane = tid & 63;
    int wm = (wave >> 1) * 64, wn = (wave & 1) * 32;
    int lr = lane & 15, lk = lane >> 4;
    int sr = tid >> 3, sc = (tid & 7) * 8;

    f32x4 acc[4][2];
    #pragma unroll
    for (int i = 0; i < 4; ++i)
        #pragma unroll
        for (int j = 0; j < 2; ++j) acc[i][j] = (f32x4){0.f, 0.f, 0.f, 0.f};

    const ushort* Ap = xbf + (size_t)(b * T + sr) * D + sc;
    const ushort* Bp = w1t + (size_t)(h * 64 + sr) * D + sc;

    uint4 ra[4], rb[2];
    #pragma unroll
    for (int e = 0; e < 4; ++e) ra[e] = *(const uint4*)(Ap + (size_t)e * 32 * D);
    #pragma unroll
    for (int e = 0; e < 2; ++e) rb[e] = *(const uint4*)(Bp + (size_t)e * 32 * D);

    for (int k0 = 0; k0 < D; k0 += 64) {
        __syncthreads();
        #pragma unroll
        for (int e = 0; e < 4; ++e) *(uint4*)&AS_(sr + e * 32, sc) = ra[e];
        if (sr < 32) {
            #pragma unroll
            for (int e = 0; e < 2; ++e) *(uint4*)&BS_(sr + e * 32, sc) = rb[e];
        }
        __syncthreads();
        if (k0 + 64 < D) {
            #pragma unroll
            for (int e = 0; e < 4; ++e)
                ra[e] = *(const uint4*)(Ap + (size_t)e * 32 * D + k0 + 64);
            #pragma unroll
            for (int e = 0; e < 2; ++e)
                rb[e] = *(const uint4*)(Bp + (size_t)e * 32 * D + k0 + 64);
        }
        #pragma unroll
        for (int ks = 0; ks < 2; ++ks) {
            short8 af[4], bfr[2];
            #pragma unroll
            for (int i = 0; i < 4; ++i)
                af[i] = *(const short8*)&AS_(wm + i * 16 + lr, ks * 32 + lk * 8);
            #pragma unroll
            for (int j = 0; j < 2; ++j)
                bfr[j] = *(const short8*)&BS_(wn + j * 16 + lr, ks * 32 + lk * 8);
            #pragma unroll
            for (int i = 0; i < 4; ++i)
                #pragma unroll
                for (int j = 0; j < 2; ++j)
                    acc[i][j] = __builtin_amdgcn_mfma_f32_16x16x32_bf16(
                        af[i], bfr[j], acc[i][j], 0, 0, 0);
        }
    }

    #pragma unroll
    for (int j = 0; j < 2; ++j) {
        int col = wn + j * 16 + lr;
        float bv = b1[h * C1 + col];
        #pragma unroll
        for (int i = 0; i < 4; ++i) {
            int t0 = wm + i * 16 + lk * 4;
            union { ushort q[4]; uint2 v; } pk;
            #pragma unroll
            for (int r = 0; r < 4; ++r) pk.q[r] = f2bf(acc[i][j][r] + bv);
            *(uint2*)&WHT_(col, t0) = pk.v;
        }
    }
    __syncthreads();

    {
        int t = tid & 127;
        bool isS = tid < 128;
        const float* av = (isS ? a1s : a1d) + h * C1;
        float s = isS ? a1b[h] : 0.f;
        #pragma unroll 8
        for (int c = 0; c < 64; ++c) s = fmaf(bf2f(WHT_(c, t)), av[c], s);
        if (isS) ss[t] = s; else ddv[t] = s;
    }
    __syncthreads();

    {
        float dm = fmaxf(ddv[lane], ddv[lane + 64]);
        #pragma unroll
        for (int msk = 1; msk < 64; msk <<= 1) dm = fmaxf(dm, __shfl_xor(dm, msk));
        int i = tid >> 1, j0 = (tid & 1) * 64;
        float si = ss[i];
        float mx = si + dm; mx = mx >= 0.f ? mx : ALPHA * mx;
        float lsum = 0.f;
        #pragma unroll
        for (int g = 0; g < 8; ++g) {
            union { ushort q[8]; uint4 v; } pk;
            #pragma unroll
            for (int e = 0; e < 8; ++e) {
                float ee = si + ddv[j0 + g * 8 + e];
                ee = ee >= 0.f ? ee : ALPHA * ee;
                float pp = __expf(ee - mx);
                lsum += pp;
                pk.q[e] = f2bf(pp);
            }
            *(uint4*)&PB_(i, j0 + g * 8) = pk.v;
        }
        lsum += __shfl_xor(lsum, 1);
        if (!(tid & 1)) sinv[i] = 1.0f / lsum;
    }
    __syncthreads();

    f32x4 acc2[4][2];
    #pragma unroll
    for (int i = 0; i < 4; ++i)
        #pragma unroll
        for (int j = 0; j < 2; ++j) acc2[i][j] = (f32x4){0.f, 0.f, 0.f, 0.f};

    #pragma unroll
    for (int ks = 0; ks < 4; ++ks) {
        short8 af[4], bfr[2];
        #pragma unroll
        for (int i = 0; i < 4; ++i)
            af[i] = *(const short8*)&PB_(wm + i * 16 + lr, ks * 32 + lk * 8);
        #pragma unroll
        for (int j = 0; j < 2; ++j)
            bfr[j] = *(const short8*)&WHT_(wn + j * 16 + lr, ks * 32 + lk * 8);
        #pragma unroll
        for (int i = 0; i < 4; ++i)
            #pragma unroll
            for (int j = 0; j < 2; ++j)
                acc2[i][j] = __builtin_amdgcn_mfma_f32_16x16x32_bf16(
                    af[i], bfr[j], acc2[i][j], 0, 0, 0);
    }

    #pragma unroll
    for (int i = 0; i < 4; ++i) {
        #pragma unroll
        for (int r = 0; r < 4; ++r) {
            int row = wm + i * 16 + lk * 4 + r;
            float sv = sinv[row];
            #pragma unroll
            for (int j = 0; j < 2; ++j) {
                int col = wn + j * 16 + lr;
                float v = acc2[i][j][r] * sv;
                v = v > 0.f ? v : 0.f;
                v = 1.0f / (1.0f + __expf(-v));
                c1[((size_t)(b * T + row)) * K2 + h * C1 + col] = f2bf(v);
            }
        }
    }
}

// ---------------------------------------------------------------------------
// Prep kernels
// ---------------------------------------------------------------------------
__global__ __launch_bounds__(256) void xbf_kernel(
    const float* __restrict__ x, ushort* __restrict__ xbf)
{
    int i = blockIdx.x * 256 + threadIdx.x;
    float4 v = *(const float4*)&x[(size_t)i * 4];
    union { ushort u[4]; uint2 p; } o;
    o.u[0] = f2bf(v.x); o.u[1] = f2bf(v.y);
    o.u[2] = f2bf(v.z); o.u[3] = f2bf(v.w);
    *(uint2*)&xbf[(size_t)i * 4] = o.p;
}

__global__ __launch_bounds__(256) void w1t_kernel(
    const float* __restrict__ W1, ushort* __restrict__ w1t)
{
    int blk = blockIdx.x; int h = blk >> 2, d0 = (blk & 3) * 64;
    __shared__ float lw[64][65];
    int tid = threadIdx.x;
    for (int e = 0; e < 16; ++e) {
        int idx = e * 256 + tid; int dr = idx >> 6, c = idx & 63;
        lw[dr][c] = W1[((size_t)h * D + d0 + dr) * C1 + c];
    }
    __syncthreads();
    for (int e = 0; e < 16; ++e) {
        int idx = e * 256 + tid; int c = idx >> 6, dr = idx & 63;
        w1t[((size_t)(h * 64 + c)) * D + d0 + dr] = f2bf(lw[dr][c]);
    }
}

__global__ __launch_bounds__(256) void w2t_kernel(
    const float* __restrict__ W2, ushort* __restrict__ w2t)
{
    int blk = blockIdx.x; int h = blk >> 5, kb = blk & 31; int k0 = kb * 128;
    __shared__ float lw[128][21];
    int tid = threadIdx.x;
    const float* src = W2 + ((size_t)h * K2 + k0) * C2;
    for (int e = 0; e < 10; ++e) {
        int idx = e * 256 + tid; int k = idx / 20, c = idx - k * 20;
        lw[k][c] = src[idx];
    }
    __syncthreads();
    for (int e = 0; e < 10; ++e) {
        int idx = e * 256 + tid; int c = idx >> 7, k = idx & 127;
        w2t[((size_t)(h * 20 + c)) * K2 + k0 + k] = f2bf(lw[k][c]);
    }
}

__global__ __launch_bounds__(256) void slwt_kernel(
    const float* __restrict__ slw, ushort* __restrict__ slwt)
{
    int blk = blockIdx.x; int kb = blk >> 2, d0 = (blk & 3) * 64; int k0 = kb * 64;
    __shared__ float lw[64][65];
    int tid = threadIdx.x;
    for (int e = 0; e < 16; ++e) {
        int idx = e * 256 + tid; int kr = idx >> 6, dc = idx & 63;
        lw[kr][dc] = slw[((size_t)(k0 + kr)) * D + d0 + dc];
    }
    __syncthreads();
    for (int e = 0; e < 16; ++e) {
        int idx = e * 256 + tid; int dr = idx >> 6, kc = idx & 63;
        slwt[((size_t)(d0 + dr)) * F2 + k0 + kc] = f2bf(lw[kc][dr]);
    }
}

// ---------------------------------------------------------------------------
// attention-2 (unchanged): reads wh2m fp32; writes c2 bf16.
// ---------------------------------------------------------------------------
__global__ __launch_bounds__(256) void attn2_kernel(
    const float* __restrict__ wh2m, const float* __restrict__ a2s,
    const float* __restrict__ a2d, const float* __restrict__ a2b,
    ushort* __restrict__ c2)
{
    int blk = blockIdx.x; int b = blk >> 6, h = blk & 63;
    __shared__ float whs[128][33];
    __shared__ alignas(16) float pT[4][128][4];
    __shared__ float ss[128], ddv[128];
    int tid = threadIdx.x; int w = tid >> 6, lane = tid & 63;
    const float* src = wh2m + (size_t)b * T * F2 + h * C2;

    for (int e = 0; e < 10; ++e) {
        int idx = e * 256 + tid; int t = idx / 20, c = idx - t * 20;
        whs[t][c] = src[(size_t)t * F2 + c];
    }
    for (int e = 0; e < 7; ++e) {
        int idx = e * 256 + tid;
        if (idx < 1664) { int t = idx / 13, c = 20 + (idx - t * 13); whs[t][c] = 0.f; }
    }
    __syncthreads();
    if (tid < 128) {
        float s = a2b[h], dv = 0.f;
        #pragma unroll
        for (int c = 0; c < 20; ++c) {
            float v = whs[tid][c];
            s  = fmaf(v, a2s[h * C2 + c], s);
            dv = fmaf(v, a2d[h * C2 + c], dv);
        }
        ss[tid] = s; ddv[tid] = dv;
    }
    __syncthreads();

    float dj0 = ddv[lane], dj1 = ddv[lane + 64];
    int cc = lane & 31, jh = lane >> 5;
    for (int q = 0; q < 8; ++q) {
        for (int r = 0; r < 4; ++r) {
            int i = w * 32 + q * 4 + r;
            float si = ss[i];
            float e0 = si + dj0; e0 = e0 >= 0.f ? e0 : ALPHA * e0;
            float e1 = si + dj1; e1 = e1 >= 0.f ? e1 : ALPHA * e1;
            float m = fmaxf(e0, e1);
            for (int msk = 1; msk < 64; msk <<= 1) m = fmaxf(m, __shfl_xor(m, msk));
            float p0 = __expf(e0 - m), p1 = __expf(e1 - m);
            float sum = p0 + p1;
            for (int msk = 1; msk < 64; msk <<= 1) sum += __shfl_xor(sum, msk);
            float inv = 1.0f / sum;
            pT[w][lane][r] = p0 * inv; pT[w][lane + 64][r] = p1 * inv;
        }
        float a0 = 0, a1 = 0, a2 = 0, a3 = 0;
        for (int jj = 0; jj < 64; ++jj) {
            int j = jh * 64 + jj;
            float4 pv = *(const float4*)&pT[w][j][0];
            float wj = whs[j][cc];
            a0 = fmaf(pv.x, wj, a0); a1 = fmaf(pv.y, wj, a1);
            a2 = fmaf(pv.z, wj, a2); a3 = fmaf(pv.w, wj, a3);
        }
        a0 += __shfl_xor(a0, 32); a1 += __shfl_xor(a1, 32);
        a2 += __shfl_xor(a2, 32); a3 += __shfl_xor(a3, 32);
        if (jh == 0 && cc < 20) {
            int i0 = w * 32 + q * 4;
            float vals[4] = {a0, a1, a2, a3};
            #pragma unroll
            for (int r = 0; r < 4; ++r) {
                float v = vals[r]; v = v > 0.f ? v : 0.f;
                v = 1.0f / (1.0f + __expf(-v));
                c2[((size_t)(b * T + i0 + r)) * F2 + h * C2 + cc] = f2bf(v);
            }
        }
    }
}

// ---------------------------------------------------------------------------
// GAR: res[b,o,d] = sum_t c3[b,t,d]*gar_w[t,o] + gar_b[o]
// ---------------------------------------------------------------------------
__global__ __launch_bounds__(256) void gar_kernel(
    const float* __restrict__ c3, const float* __restrict__ garw,
    const float* __restrict__ garb, float* __restrict__ out)
{
    int blk = blockIdx.x; int b = blk >> 5, o = blk & 31;
    int dcol = threadIdx.x;
    float acc = garb[o];
    const float* cp = c3 + (size_t)b * T * D + dcol;
    for (int t = 0; t < T; ++t)
        acc = fmaf(cp[(size_t)t * D], garw[t * OUTW + o], acc);
    out[((size_t)b * OUTW + o) * D + dcol] = acc;
}

// ---------------------------------------------------------------------------
extern "C" void kernel_launch(void* const* d_in, const int* in_sizes, int n_in,
                              void* d_out, int out_size, void* d_ws, size_t ws_size,
                              hipStream_t stream) {
    const float* x    = (const float*)d_in[0];
    const float* W1   = (const float*)d_in[1];
    const float* b1   = (const float*)d_in[2];
    const float* a1s  = (const float*)d_in[3];
    const float* a1d  = (const float*)d_in[4];
    const float* a1b  = (const float*)d_in[5];
    const float* W2   = (const float*)d_in[6];
    const float* b2   = (const float*)d_in[7];
    const float* a2s  = (const float*)d_in[8];
    const float* a2d  = (const float*)d_in[9];
    const float* a2b  = (const float*)d_in[10];
    const float* slw  = (const float*)d_in[11];
    const float* slb  = (const float*)d_in[12];
    const float* garw = (const float*)d_in[13];
    const float* garb = (const float*)d_in[14];

    char* p = (char*)d_ws;
    float*  wh2m  = (float*)p;   p += (size_t)2048 * 1280 * 4;     // 10.5 MB
    float*  c3    = (float*)p;   p += (size_t)2048 * 256  * 4;     //  2.1 MB
    ushort* xbf   = (ushort*)p;  p += (size_t)2048 * 256  * 2;     //  1.0 MB
    ushort* w1t   = (ushort*)p;  p += (size_t)4096 * 256  * 2;     //  2.1 MB
    ushort* c1bf  = (ushort*)p;  p += (size_t)2048 * 4096 * 2;     // 16.8 MB
    ushort* w2t   = (ushort*)p;  p += (size_t)1280 * 4096 * 2;     // 10.5 MB
    ushort* c2bf  = (ushort*)p;  p += (size_t)2048 * 1280 * 2;     //  5.2 MB
    ushort* slwt  = (ushort*)p;  p += (size_t)256  * 1280 * 2;     //  0.7 MB
    ushort* wh2pb = (ushort*)p;  p += (size_t)8 * 2048 * 1280 * 2; // 42 MB
    ushort* c3pb  = (ushort*)c1bf;   // aliases c1bf (dead after gemm2 reads it)

    xbf_kernel <<<512,  256, 0, stream>>>(x, xbf);
    w1t_kernel <<<256,  256, 0, stream>>>(W1, w1t);
    w2t_kernel <<<2048, 256, 0, stream>>>(W2, w2t);
    slwt_kernel<<<80,   256, 0, stream>>>(slw, slwt);

    fused1_kernel<<<B * H, 256, 0, stream>>>(xbf, w1t, b1, a1s, a1d, a1b, c1bf);

    gemm_splitk_kernel<4096, 10, 16, 8><<<1280, 256, 0, stream>>>(c1bf, w2t, wh2pb);
    reduce_bias_kernel<8, 1280><<<2560, 256, 0, stream>>>(wh2pb, b2, wh2m,
                                                          2048 * 1280);
    attn2_kernel<<<B * H, 256, 0, stream>>>(wh2m, a2s, a2d, a2b, c2bf);

    gemm_splitk_kernel<1280, 2, 16, 4><<<128, 256, 0, stream>>>(c2bf, slwt, c3pb);
    reduce_bias_kernel<4, 256><<<512, 256, 0, stream>>>(c3pb, slb, c3, 2048 * 256);

    gar_kernel<<<B * OUTW, 256, 0, stream>>>(c3, garw, garb, (float*)d_out);
}

// Round 9
// 149.470 us; speedup vs baseline: 2.7369x; 1.1771x over previous
//
#include <hip/hip_runtime.h>
#include <hip/hip_bf16.h>

#define B 16
#define T 128
#define D 256
#define H 64
#define C1 64
#define C2 20
#define K2 4096   // H*C1
#define F2 1280   // H*C2
#define OUTW 32
#define ALPHA 0.2f

typedef __attribute__((ext_vector_type(8))) short short8;
typedef __attribute__((ext_vector_type(4))) float f32x4;

static __device__ __forceinline__ ushort f2bf(float f) {
    __hip_bfloat16 h = __float2bfloat16(f);
    return *reinterpret_cast<ushort*>(&h);
}
static __device__ __forceinline__ float bf2f(ushort u) {
    return __uint_as_float(((unsigned int)u) << 16);
}
// async global->LDS, 16B per lane; LDS dest is wave-uniform base + lane*16.
static __device__ __forceinline__ void gload16(const ushort* g, ushort* l) {
    __builtin_amdgcn_global_load_lds((const unsigned int*)g, (unsigned int*)l,
                                     16, 0, 0);
}

// ---------------------------------------------------------------------------
// Split-K MFMA GEMM v2 (verified round 8): global_load_lds staging, linear
// LDS, bf16 partials. 128x128 tile, BK=64, 4 waves, 16x16x32 bf16.
// ---------------------------------------------------------------------------
template<int KD, int NBLK, int MBLK, int KSPLIT>
__global__ __launch_bounds__(256) void gemm_splitk_kernel(
    const ushort* __restrict__ Ag, const ushort* __restrict__ Bg,
    ushort* __restrict__ Cp)
{
    __shared__ ushort As[128 * 64];
    __shared__ ushort Bs[128 * 64];
    constexpr int NN = NBLK * 128;
    constexpr int MM = MBLK * 128;
    constexpr int NT = MBLK * NBLK;
    constexpr int TOTAL = NT * KSPLIT;
    constexpr int KDP = KD / KSPLIT;
    static_assert(TOTAL % 8 == 0, "swizzle needs multiple of 8 blocks");

    int tid = threadIdx.x;
    int bid = blockIdx.x;
    int wg = (bid & 7) * (TOTAL / 8) + (bid >> 3);
    int kp = wg / NT; int tile = wg - kp * NT;
    int bm = (tile / NBLK) * 128, bn = (tile % NBLK) * 128;

    int wave = tid >> 6, lane = tid & 63;
    int wm = (wave >> 1) * 64, wn = (wave & 1) * 64;
    int lr = lane & 15, lk = lane >> 4;
    int srow = lane >> 3, scol = (lane & 7) * 8;

    f32x4 acc[4][4];
    #pragma unroll
    for (int i = 0; i < 4; ++i)
        #pragma unroll
        for (int j = 0; j < 4; ++j) acc[i][j] = (f32x4){0.f, 0.f, 0.f, 0.f};

    const ushort* ApB = Ag + (size_t)bm * KD + kp * KDP;
    const ushort* BpB = Bg + (size_t)bn * KD + kp * KDP;

    for (int k0 = 0; k0 < KDP; k0 += 64) {
        __syncthreads();
        #pragma unroll
        for (int e = 0; e < 4; ++e) {
            int c = e * 4 + wave;
            gload16(ApB + (size_t)(8 * c + srow) * KD + k0 + scol, &As[c * 512]);
            gload16(BpB + (size_t)(8 * c + srow) * KD + k0 + scol, &Bs[c * 512]);
        }
        __syncthreads();
        #pragma unroll
        for (int ks = 0; ks < 2; ++ks) {
            short8 af[4], bfr[4];
            #pragma unroll
            for (int i = 0; i < 4; ++i)
                af[i] = *(const short8*)&As[(wm + i * 16 + lr) * 64 + ks * 32 + lk * 8];
            #pragma unroll
            for (int j = 0; j < 4; ++j)
                bfr[j] = *(const short8*)&Bs[(wn + j * 16 + lr) * 64 + ks * 32 + lk * 8];
            #pragma unroll
            for (int i = 0; i < 4; ++i)
                #pragma unroll
                for (int j = 0; j < 4; ++j)
                    acc[i][j] = __builtin_amdgcn_mfma_f32_16x16x32_bf16(
                        af[i], bfr[j], acc[i][j], 0, 0, 0);
        }
    }

    ushort* Cout = Cp + (size_t)kp * MM * NN;
    #pragma unroll
    for (int i = 0; i < 4; ++i) {
        #pragma unroll
        for (int j = 0; j < 4; ++j) {
            int col = bn + wn + j * 16 + lr;
            #pragma unroll
            for (int r = 0; r < 4; ++r) {
                int row = bm + wm + i * 16 + lk * 4 + r;
                Cout[(size_t)row * NN + col] = f2bf(acc[i][j][r]);
            }
        }
    }
}

// ---------------------------------------------------------------------------
// reduce P bf16 split-K partials + bias -> fp32 out (still used for sl).
// ---------------------------------------------------------------------------
template<int P, int NN>
__global__ __launch_bounds__(256) void reduce_bias_kernel(
    const ushort* __restrict__ parts, const float* __restrict__ bias,
    float* __restrict__ out, int MN)
{
    size_t off = ((size_t)blockIdx.x * 256 + threadIdx.x) * 4;
    float s0 = 0.f, s1 = 0.f, s2 = 0.f, s3 = 0.f;
    #pragma unroll
    for (int p = 0; p < P; ++p) {
        uint2 v = *(const uint2*)&parts[(size_t)p * MN + off];
        s0 += bf2f((ushort)(v.x & 0xffff));
        s1 += bf2f((ushort)(v.x >> 16));
        s2 += bf2f((ushort)(v.y & 0xffff));
        s3 += bf2f((ushort)(v.y >> 16));
    }
    float4 bv = *(const float4*)&bias[(int)(off % NN)];
    float4 o; o.x = s0 + bv.x; o.y = s1 + bv.y; o.z = s2 + bv.z; o.w = s3 + bv.w;
    *(float4*)&out[off] = o;
}

// ---------------------------------------------------------------------------
// FUSED kernel 1 (verified round 7): Wh1 MFMA -> scores -> P~ -> PV MFMA.
// ---------------------------------------------------------------------------
#define AS_(r,c)  u.stag[(r) * 72 + (c)]
#define BS_(r,c)  u.stag[9216 + (r) * 72 + (c)]
#define PB_(r,c)  u.Pb[(r) * 136 + (c)]
#define WHT_(r,c) whT[(r) * 136 + (c)]

__global__ __launch_bounds__(256) void fused1_kernel(
    const ushort* __restrict__ xbf,   // [B*T][256] bf16
    const ushort* __restrict__ w1t,   // [H*64][256] bf16
    const float* __restrict__ b1,     // [4096] ([h][c] flat)
    const float* __restrict__ a1s, const float* __restrict__ a1d,
    const float* __restrict__ a1b,
    ushort* __restrict__ c1)
{
    int blk = blockIdx.x; int b = blk >> 6, h = blk & 63;
    __shared__ union {
        ushort stag[128 * 72 + 64 * 72];
        ushort Pb[128 * 136];
    } u;
    __shared__ ushort whT[64 * 136];
    __shared__ float ss[128], ddv[128], sinv[128];

    int tid = threadIdx.x;
    int wave = tid >> 6, lane = tid & 63;
    int wm = (wave >> 1) * 64, wn = (wave & 1) * 32;
    int lr = lane & 15, lk = lane >> 4;
    int sr = tid >> 3, sc = (tid & 7) * 8;

    f32x4 acc[4][2];
    #pragma unroll
    for (int i = 0; i < 4; ++i)
        #pragma unroll
        for (int j = 0; j < 2; ++j) acc[i][j] = (f32x4){0.f, 0.f, 0.f, 0.f};

    const ushort* Ap = xbf + (size_t)(b * T + sr) * D + sc;
    const ushort* Bp = w1t + (size_t)(h * 64 + sr) * D + sc;

    uint4 ra[4], rb[2];
    #pragma unroll
    for (int e = 0; e < 4; ++e) ra[e] = *(const uint4*)(Ap + (size_t)e * 32 * D);
    #pragma unroll
    for (int e = 0; e < 2; ++e) rb[e] = *(const uint4*)(Bp + (size_t)e * 32 * D);

    for (int k0 = 0; k0 < D; k0 += 64) {
        __syncthreads();
        #pragma unroll
        for (int e = 0; e < 4; ++e) *(uint4*)&AS_(sr + e * 32, sc) = ra[e];
        if (sr < 32) {
            #pragma unroll
            for (int e = 0; e < 2; ++e) *(uint4*)&BS_(sr + e * 32, sc) = rb[e];
        }
        __syncthreads();
        if (k0 + 64 < D) {
            #pragma unroll
            for (int e = 0; e < 4; ++e)
                ra[e] = *(const uint4*)(Ap + (size_t)e * 32 * D + k0 + 64);
            #pragma unroll
            for (int e = 0; e < 2; ++e)
                rb[e] = *(const uint4*)(Bp + (size_t)e * 32 * D + k0 + 64);
        }
        #pragma unroll
        for (int ks = 0; ks < 2; ++ks) {
            short8 af[4], bfr[2];
            #pragma unroll
            for (int i = 0; i < 4; ++i)
                af[i] = *(const short8*)&AS_(wm + i * 16 + lr, ks * 32 + lk * 8);
            #pragma unroll
            for (int j = 0; j < 2; ++j)
                bfr[j] = *(const short8*)&BS_(wn + j * 16 + lr, ks * 32 + lk * 8);
            #pragma unroll
            for (int i = 0; i < 4; ++i)
                #pragma unroll
                for (int j = 0; j < 2; ++j)
                    acc[i][j] = __builtin_amdgcn_mfma_f32_16x16x32_bf16(
                        af[i], bfr[j], acc[i][j], 0, 0, 0);
        }
    }

    #pragma unroll
    for (int j = 0; j < 2; ++j) {
        int col = wn + j * 16 + lr;
        float bv = b1[h * C1 + col];
        #pragma unroll
        for (int i = 0; i < 4; ++i) {
            int t0 = wm + i * 16 + lk * 4;
            union { ushort q[4]; uint2 v; } pk;
            #pragma unroll
            for (int r = 0; r < 4; ++r) pk.q[r] = f2bf(acc[i][j][r] + bv);
            *(uint2*)&WHT_(col, t0) = pk.v;
        }
    }
    __syncthreads();

    {
        int t = tid & 127;
        bool isS = tid < 128;
        const float* av = (isS ? a1s : a1d) + h * C1;
        float s = isS ? a1b[h] : 0.f;
        #pragma unroll 8
        for (int c = 0; c < 64; ++c) s = fmaf(bf2f(WHT_(c, t)), av[c], s);
        if (isS) ss[t] = s; else ddv[t] = s;
    }
    __syncthreads();

    {
        float dm = fmaxf(ddv[lane], ddv[lane + 64]);
        #pragma unroll
        for (int msk = 1; msk < 64; msk <<= 1) dm = fmaxf(dm, __shfl_xor(dm, msk));
        int i = tid >> 1, j0 = (tid & 1) * 64;
        float si = ss[i];
        float mx = si + dm; mx = mx >= 0.f ? mx : ALPHA * mx;
        float lsum = 0.f;
        #pragma unroll
        for (int g = 0; g < 8; ++g) {
            union { ushort q[8]; uint4 v; } pk;
            #pragma unroll
            for (int e = 0; e < 8; ++e) {
                float ee = si + ddv[j0 + g * 8 + e];
                ee = ee >= 0.f ? ee : ALPHA * ee;
                float pp = __expf(ee - mx);
                lsum += pp;
                pk.q[e] = f2bf(pp);
            }
            *(uint4*)&PB_(i, j0 + g * 8) = pk.v;
        }
        lsum += __shfl_xor(lsum, 1);
        if (!(tid & 1)) sinv[i] = 1.0f / lsum;
    }
    __syncthreads();

    f32x4 acc2[4][2];
    #pragma unroll
    for (int i = 0; i < 4; ++i)
        #pragma unroll
        for (int j = 0; j < 2; ++j) acc2[i][j] = (f32x4){0.f, 0.f, 0.f, 0.f};

    #pragma unroll
    for (int ks = 0; ks < 4; ++ks) {
        short8 af[4], bfr[2];
        #pragma unroll
        for (int i = 0; i < 4; ++i)
            af[i] = *(const short8*)&PB_(wm + i * 16 + lr, ks * 32 + lk * 8);
        #pragma unroll
        for (int j = 0; j < 2; ++j)
            bfr[j] = *(const short8*)&WHT_(wn + j * 16 + lr, ks * 32 + lk * 8);
        #pragma unroll
        for (int i = 0; i < 4; ++i)
            #pragma unroll
            for (int j = 0; j < 2; ++j)
                acc2[i][j] = __builtin_amdgcn_mfma_f32_16x16x32_bf16(
                    af[i], bfr[j], acc2[i][j], 0, 0, 0);
    }

    #pragma unroll
    for (int i = 0; i < 4; ++i) {
        #pragma unroll
        for (int r = 0; r < 4; ++r) {
            int row = wm + i * 16 + lk * 4 + r;
            float sv = sinv[row];
            #pragma unroll
            for (int j = 0; j < 2; ++j) {
                int col = wn + j * 16 + lr;
                float v = acc2[i][j][r] * sv;
                v = v > 0.f ? v : 0.f;
                v = 1.0f / (1.0f + __expf(-v));
                c1[((size_t)(b * T + row)) * K2 + h * C1 + col] = f2bf(v);
            }
        }
    }
}

// ---------------------------------------------------------------------------
// FUSED kernel 2: per (b,h): sum 8 split-K bf16 partials (+bias b2) ->
// whT2[c][t] bf16 (c padded to 32) -> scores -> P~ -> PV MFMA -> c2 bf16.
// Replaces reduce_bias<8> + attn2.
// ---------------------------------------------------------------------------
#define PB2_(r,c)  Pb2[(r) * 136 + (c)]
#define WHT2_(r,c) whT2[(r) * 136 + (c)]

__global__ __launch_bounds__(256) void fused2_kernel(
    const ushort* __restrict__ wh2pb,  // [8][2048][1280] bf16 partials
    const float* __restrict__ b2,      // [1280] ([h][c] flat)
    const float* __restrict__ a2s, const float* __restrict__ a2d,
    const float* __restrict__ a2b,
    ushort* __restrict__ c2)
{
    int blk = blockIdx.x; int b = blk >> 6, h = blk & 63;
    __shared__ ushort Pb2[128 * 136];
    __shared__ ushort whT2[32 * 136];
    __shared__ float ss[128], ddv[128], sinv[128];

    int tid = threadIdx.x;
    int wave = tid >> 6, lane = tid & 63;
    int lr = lane & 15, lk = lane >> 4;
    constexpr int MN = 2048 * F2;

    // ---- load + split-K reduce + transpose ----
    const ushort* base = wh2pb + (size_t)(b * T) * F2 + h * C2;
    for (int e = 0; e < 10; ++e) {
        int idx = e * 256 + tid;               // 0..2559
        int t = idx / 20, c = idx - t * 20;
        size_t off = (size_t)t * F2 + c;
        float s = b2[h * C2 + c];
        #pragma unroll
        for (int p = 0; p < 8; ++p) s += bf2f(base[(size_t)p * MN + off]);
        WHT2_(c, t) = f2bf(s);
    }
    {   // zero-pad rows 20..31
        int idx = tid;                          // 12*128 = 1536 entries
        for (int e = 0; e < 6; ++e, idx += 256) {
            int c = 20 + (idx >> 7), t = idx & 127;
            WHT2_(c, t) = 0;
        }
    }
    __syncthreads();

    // ---- scores ----
    {
        int t = tid & 127;
        bool isS = tid < 128;
        const float* av = (isS ? a2s : a2d) + h * C2;
        float s = isS ? a2b[h] : 0.f;
        #pragma unroll
        for (int c = 0; c < 20; ++c) s = fmaf(bf2f(WHT2_(c, t)), av[c], s);
        if (isS) ss[t] = s; else ddv[t] = s;
    }
    __syncthreads();

    // ---- P~ + row sums (verified fused1 phase C) ----
    {
        float dm = fmaxf(ddv[lane], ddv[lane + 64]);
        #pragma unroll
        for (int msk = 1; msk < 64; msk <<= 1) dm = fmaxf(dm, __shfl_xor(dm, msk));
        int i = tid >> 1, j0 = (tid & 1) * 64;
        float si = ss[i];
        float mx = si + dm; mx = mx >= 0.f ? mx : ALPHA * mx;
        float lsum = 0.f;
        #pragma unroll
        for (int g = 0; g < 8; ++g) {
            union { ushort q[8]; uint4 v; } pk;
            #pragma unroll
            for (int e = 0; e < 8; ++e) {
                float ee = si + ddv[j0 + g * 8 + e];
                ee = ee >= 0.f ? ee : ALPHA * ee;
                float pp = __expf(ee - mx);
                lsum += pp;
                pk.q[e] = f2bf(pp);
            }
            *(uint4*)&PB2_(i, j0 + g * 8) = pk.v;
        }
        lsum += __shfl_xor(lsum, 1);
        if (!(tid & 1)) sinv[i] = 1.0f / lsum;
    }
    __syncthreads();

    // ---- PV: out[128][32] = P~ @ whT2^T; wave owns 32 rows ----
    int wm2 = wave * 32;
    f32x4 acc2[2][2];
    #pragma unroll
    for (int i = 0; i < 2; ++i)
        #pragma unroll
        for (int j = 0; j < 2; ++j) acc2[i][j] = (f32x4){0.f, 0.f, 0.f, 0.f};

    #pragma unroll
    for (int ks = 0; ks < 4; ++ks) {
        short8 af[2], bfr[2];
        #pragma unroll
        for (int i = 0; i < 2; ++i)
            af[i] = *(const short8*)&PB2_(wm2 + i * 16 + lr, ks * 32 + lk * 8);
        #pragma unroll
        for (int j = 0; j < 2; ++j)
            bfr[j] = *(const short8*)&WHT2_(j * 16 + lr, ks * 32 + lk * 8);
        #pragma unroll
        for (int i = 0; i < 2; ++i)
            #pragma unroll
            for (int j = 0; j < 2; ++j)
                acc2[i][j] = __builtin_amdgcn_mfma_f32_16x16x32_bf16(
                    af[i], bfr[j], acc2[i][j], 0, 0, 0);
    }

    #pragma unroll
    for (int i = 0; i < 2; ++i) {
        #pragma unroll
        for (int r = 0; r < 4; ++r) {
            int row = wm2 + i * 16 + lk * 4 + r;
            float sv = sinv[row];
            #pragma unroll
            for (int j = 0; j < 2; ++j) {
                int col = j * 16 + lr;
                if (col < C2) {
                    float v = acc2[i][j][r] * sv;
                    v = v > 0.f ? v : 0.f;
                    v = 1.0f / (1.0f + __expf(-v));
                    c2[((size_t)(b * T + row)) * F2 + h * C2 + col] = f2bf(v);
                }
            }
        }
    }
}

// ---------------------------------------------------------------------------
// Prep kernels
// ---------------------------------------------------------------------------
__global__ __launch_bounds__(256) void xbf_kernel(
    const float* __restrict__ x, ushort* __restrict__ xbf)
{
    int i = blockIdx.x * 256 + threadIdx.x;
    float4 v = *(const float4*)&x[(size_t)i * 4];
    union { ushort u[4]; uint2 p; } o;
    o.u[0] = f2bf(v.x); o.u[1] = f2bf(v.y);
    o.u[2] = f2bf(v.z); o.u[3] = f2bf(v.w);
    *(uint2*)&xbf[(size_t)i * 4] = o.p;
}

__global__ __launch_bounds__(256) void w1t_kernel(
    const float* __restrict__ W1, ushort* __restrict__ w1t)
{
    int blk = blockIdx.x; int h = blk >> 2, d0 = (blk & 3) * 64;
    __shared__ float lw[64][65];
    int tid = threadIdx.x;
    for (int e = 0; e < 16; ++e) {
        int idx = e * 256 + tid; int dr = idx >> 6, c = idx & 63;
        lw[dr][c] = W1[((size_t)h * D + d0 + dr) * C1 + c];
    }
    __syncthreads();
    for (int e = 0; e < 16; ++e) {
        int idx = e * 256 + tid; int c = idx >> 6, dr = idx & 63;
        w1t[((size_t)(h * 64 + c)) * D + d0 + dr] = f2bf(lw[dr][c]);
    }
}

__global__ __launch_bounds__(256) void w2t_kernel(
    const float* __restrict__ W2, ushort* __restrict__ w2t)
{
    int blk = blockIdx.x; int h = blk >> 5, kb = blk & 31; int k0 = kb * 128;
    __shared__ float lw[128][21];
    int tid = threadIdx.x;
    const float* src = W2 + ((size_t)h * K2 + k0) * C2;
    for (int e = 0; e < 10; ++e) {
        int idx = e * 256 + tid; int k = idx / 20, c = idx - k * 20;
        lw[k][c] = src[idx];
    }
    __syncthreads();
    for (int e = 0; e < 10; ++e) {
        int idx = e * 256 + tid; int c = idx >> 7, k = idx & 127;
        w2t[((size_t)(h * 20 + c)) * K2 + k0 + k] = f2bf(lw[k][c]);
    }
}

__global__ __launch_bounds__(256) void slwt_kernel(
    const float* __restrict__ slw, ushort* __restrict__ slwt)
{
    int blk = blockIdx.x; int kb = blk >> 2, d0 = (blk & 3) * 64; int k0 = kb * 64;
    __shared__ float lw[64][65];
    int tid = threadIdx.x;
    for (int e = 0; e < 16; ++e) {
        int idx = e * 256 + tid; int kr = idx >> 6, dc = idx & 63;
        lw[kr][dc] = slw[((size_t)(k0 + kr)) * D + d0 + dc];
    }
    __syncthreads();
    for (int e = 0; e < 16; ++e) {
        int idx = e * 256 + tid; int dr = idx >> 6, kc = idx & 63;
        slwt[((size_t)(d0 + dr)) * F2 + k0 + kc] = f2bf(lw[kc][dr]);
    }
}

// ---------------------------------------------------------------------------
// GAR: res[b,o,d] = sum_t c3[b,t,d]*gar_w[t,o] + gar_b[o]
// ---------------------------------------------------------------------------
__global__ __launch_bounds__(256) void gar_kernel(
    const float* __restrict__ c3, const float* __restrict__ garw,
    const float* __restrict__ garb, float* __restrict__ out)
{
    int blk = blockIdx.x; int b = blk >> 5, o = blk & 31;
    int dcol = threadIdx.x;
    float acc = garb[o];
    const float* cp = c3 + (size_t)b * T * D + dcol;
    for (int t = 0; t < T; ++t)
        acc = fmaf(cp[(size_t)t * D], garw[t * OUTW + o], acc);
    out[((size_t)b * OUTW + o) * D + dcol] = acc;
}

// ---------------------------------------------------------------------------
extern "C" void kernel_launch(void* const* d_in, const int* in_sizes, int n_in,
                              void* d_out, int out_size, void* d_ws, size_t ws_size,
                              hipStream_t stream) {
    const float* x    = (const float*)d_in[0];
    const float* W1   = (const float*)d_in[1];
    const float* b1   = (const float*)d_in[2];
    const float* a1s  = (const float*)d_in[3];
    const float* a1d  = (const float*)d_in[4];
    const float* a1b  = (const float*)d_in[5];
    const float* W2   = (const float*)d_in[6];
    const float* b2   = (const float*)d_in[7];
    const float* a2s  = (const float*)d_in[8];
    const float* a2d  = (const float*)d_in[9];
    const float* a2b  = (const float*)d_in[10];
    const float* slw  = (const float*)d_in[11];
    const float* slb  = (const float*)d_in[12];
    const float* garw = (const float*)d_in[13];
    const float* garb = (const float*)d_in[14];

    char* p = (char*)d_ws;
    float*  c3    = (float*)p;   p += (size_t)2048 * 256  * 4;     //  2.1 MB
    ushort* xbf   = (ushort*)p;  p += (size_t)2048 * 256  * 2;     //  1.0 MB
    ushort* w1t   = (ushort*)p;  p += (size_t)4096 * 256  * 2;     //  2.1 MB
    ushort* c1bf  = (ushort*)p;  p += (size_t)2048 * 4096 * 2;     // 16.8 MB
    ushort* w2t   = (ushort*)p;  p += (size_t)1280 * 4096 * 2;     // 10.5 MB
    ushort* c2bf  = (ushort*)p;  p += (size_t)2048 * 1280 * 2;     //  5.2 MB
    ushort* slwt  = (ushort*)p;  p += (size_t)256  * 1280 * 2;     //  0.7 MB
    ushort* wh2pb = (ushort*)p;  p += (size_t)8 * 2048 * 1280 * 2; // 42 MB
    ushort* c3pb  = (ushort*)c1bf;   // aliases c1bf (dead after gemm2 reads it)

    xbf_kernel <<<512,  256, 0, stream>>>(x, xbf);
    w1t_kernel <<<256,  256, 0, stream>>>(W1, w1t);
    w2t_kernel <<<2048, 256, 0, stream>>>(W2, w2t);
    slwt_kernel<<<80,   256, 0, stream>>>(slw, slwt);

    fused1_kernel<<<B * H, 256, 0, stream>>>(xbf, w1t, b1, a1s, a1d, a1b, c1bf);

    gemm_splitk_kernel<4096, 10, 16, 8><<<1280, 256, 0, stream>>>(c1bf, w2t, wh2pb);
    fused2_kernel<<<B * H, 256, 0, stream>>>(wh2pb, b2, a2s, a2d, a2b, c2bf);

    gemm_splitk_kernel<1280, 2, 16, 4><<<128, 256, 0, stream>>>(c2bf, slwt, c3pb);
    reduce_bias_kernel<4, 256><<<512, 256, 0, stream>>>(c3pb, slb, c3, 2048 * 256);

    gar_kernel<<<B * OUTW, 256, 0, stream>>>(c3, garw, garb, (float*)d_out);
}

// Round 11
// 131.597 us; speedup vs baseline: 3.1086x; 1.1358x over previous
//
#include <hip/hip_runtime.h>
#include <hip/hip_bf16.h>

#define B 16
#define T 128
#define D 256
#define H 64
#define C1 64
#define C2 20
#define K2 4096   // H*C1
#define F2 1280   // H*C2
#define OUTW 32
#define ALPHA 0.2f

typedef __attribute__((ext_vector_type(8))) short short8;
typedef __attribute__((ext_vector_type(4))) float f32x4;

static __device__ __forceinline__ ushort f2bf(float f) {
    __hip_bfloat16 h = __float2bfloat16(f);
    return *reinterpret_cast<ushort*>(&h);
}
static __device__ __forceinline__ float bf2f(ushort u) {
    return __uint_as_float(((unsigned int)u) << 16);
}
// async global->LDS, 16B per lane; LDS dest is wave-uniform base + lane*16.
static __device__ __forceinline__ void gload16(const ushort* g, ushort* l) {
    __builtin_amdgcn_global_load_lds((const unsigned int*)g, (unsigned int*)l,
                                     16, 0, 0);
}

// ---------------------------------------------------------------------------
// Split-K MFMA GEMM (verified round 8) + PERM epilogue:
// PERM=1 -> fragment-native layout, fully coalesced uint2 stores:
//   addr = kp*MM*NN + tile*16384 + wave*4096 + (i*4+j)*256 + lane*4 + r
// PERM=0 -> row-major scalar stores (legacy, for the small sl GEMM).
// ---------------------------------------------------------------------------
template<int KD, int NBLK, int MBLK, int KSPLIT, int PERM>
__global__ __launch_bounds__(256) void gemm_splitk_kernel(
    const ushort* __restrict__ Ag, const ushort* __restrict__ Bg,
    ushort* __restrict__ Cp)
{
    __shared__ ushort As[128 * 64];
    __shared__ ushort Bs[128 * 64];
    constexpr int NN = NBLK * 128;
    constexpr int MM = MBLK * 128;
    constexpr int NT = MBLK * NBLK;
    constexpr int TOTAL = NT * KSPLIT;
    constexpr int KDP = KD / KSPLIT;
    static_assert(TOTAL % 8 == 0, "swizzle needs multiple of 8 blocks");

    int tid = threadIdx.x;
    int bid = blockIdx.x;
    int wg = (bid & 7) * (TOTAL / 8) + (bid >> 3);
    int kp = wg / NT; int tile = wg - kp * NT;
    int bm = (tile / NBLK) * 128, bn = (tile % NBLK) * 128;

    int wave = tid >> 6, lane = tid & 63;
    int wm = (wave >> 1) * 64, wn = (wave & 1) * 64;
    int lr = lane & 15, lk = lane >> 4;
    int srow = lane >> 3, scol = (lane & 7) * 8;

    f32x4 acc[4][4];
    #pragma unroll
    for (int i = 0; i < 4; ++i)
        #pragma unroll
        for (int j = 0; j < 4; ++j) acc[i][j] = (f32x4){0.f, 0.f, 0.f, 0.f};

    const ushort* ApB = Ag + (size_t)bm * KD + kp * KDP;
    const ushort* BpB = Bg + (size_t)bn * KD + kp * KDP;

    for (int k0 = 0; k0 < KDP; k0 += 64) {
        __syncthreads();
        #pragma unroll
        for (int e = 0; e < 4; ++e) {
            int c = e * 4 + wave;
            gload16(ApB + (size_t)(8 * c + srow) * KD + k0 + scol, &As[c * 512]);
            gload16(BpB + (size_t)(8 * c + srow) * KD + k0 + scol, &Bs[c * 512]);
        }
        __syncthreads();
        #pragma unroll
        for (int ks = 0; ks < 2; ++ks) {
            short8 af[4], bfr[4];
            #pragma unroll
            for (int i = 0; i < 4; ++i)
                af[i] = *(const short8*)&As[(wm + i * 16 + lr) * 64 + ks * 32 + lk * 8];
            #pragma unroll
            for (int j = 0; j < 4; ++j)
                bfr[j] = *(const short8*)&Bs[(wn + j * 16 + lr) * 64 + ks * 32 + lk * 8];
            #pragma unroll
            for (int i = 0; i < 4; ++i)
                #pragma unroll
                for (int j = 0; j < 4; ++j)
                    acc[i][j] = __builtin_amdgcn_mfma_f32_16x16x32_bf16(
                        af[i], bfr[j], acc[i][j], 0, 0, 0);
        }
    }

    if constexpr (PERM) {
        ushort* Cw = Cp + (size_t)kp * MM * NN + (size_t)tile * 16384
                   + wave * 4096 + lane * 4;
        #pragma unroll
        for (int i = 0; i < 4; ++i)
            #pragma unroll
            for (int j = 0; j < 4; ++j) {
                union { ushort q[4]; uint2 v; } pk;
                #pragma unroll
                for (int r = 0; r < 4; ++r) pk.q[r] = f2bf(acc[i][j][r]);
                *(uint2*)&Cw[(i * 4 + j) * 256] = pk.v;
            }
    } else {
        ushort* Cout = Cp + (size_t)kp * MM * NN;
        #pragma unroll
        for (int i = 0; i < 4; ++i) {
            #pragma unroll
            for (int j = 0; j < 4; ++j) {
                int col = bn + wn + j * 16 + lr;
                #pragma unroll
                for (int r = 0; r < 4; ++r) {
                    int row = bm + wm + i * 16 + lk * 4 + r;
                    Cout[(size_t)row * NN + col] = f2bf(acc[i][j][r]);
                }
            }
        }
    }
}

// ---------------------------------------------------------------------------
// reduce P bf16 split-K partials + bias -> fp32 out (sl path, PERM=0 layout).
// ---------------------------------------------------------------------------
template<int P, int NN>
__global__ __launch_bounds__(256) void reduce_bias_kernel(
    const ushort* __restrict__ parts, const float* __restrict__ bias,
    float* __restrict__ out, int MN)
{
    size_t off = ((size_t)blockIdx.x * 256 + threadIdx.x) * 4;
    float s0 = 0.f, s1 = 0.f, s2 = 0.f, s3 = 0.f;
    #pragma unroll
    for (int p = 0; p < P; ++p) {
        uint2 v = *(const uint2*)&parts[(size_t)p * MN + off];
        s0 += bf2f((ushort)(v.x & 0xffff));
        s1 += bf2f((ushort)(v.x >> 16));
        s2 += bf2f((ushort)(v.y & 0xffff));
        s3 += bf2f((ushort)(v.y >> 16));
    }
    float4 bv = *(const float4*)&bias[(int)(off % NN)];
    float4 o; o.x = s0 + bv.x; o.y = s1 + bv.y; o.z = s2 + bv.z; o.w = s3 + bv.w;
    *(float4*)&out[off] = o;
}

// ---------------------------------------------------------------------------
// FUSED kernel 1 (verified round 7) + coalesced c1 epilogue via LDS restage.
// ---------------------------------------------------------------------------
#define AS_(r,c)  u.stag[(r) * 72 + (c)]
#define BS_(r,c)  u.stag[9216 + (r) * 72 + (c)]
#define PB_(r,c)  u.Pb[(r) * 136 + (c)]
#define WHT_(r,c) whT[(r) * 136 + (c)]

__global__ __launch_bounds__(256) void fused1_kernel(
    const ushort* __restrict__ xbf,   // [B*T][256] bf16
    const ushort* __restrict__ w1t,   // [H*64][256] bf16
    const float* __restrict__ b1,     // [4096] ([h][c] flat)
    const float* __restrict__ a1s, const float* __restrict__ a1d,
    const float* __restrict__ a1b,
    ushort* __restrict__ c1)
{
    int blk = blockIdx.x; int b = blk >> 6, h = blk & 63;
    __shared__ union {
        ushort stag[128 * 72 + 64 * 72];
        ushort Pb[128 * 136];
    } u;
    __shared__ ushort whT[64 * 136];
    __shared__ float ss[128], ddv[128], sinv[128];

    int tid = threadIdx.x;
    int wave = tid >> 6, lane = tid & 63;
    int wm = (wave >> 1) * 64, wn = (wave & 1) * 32;
    int lr = lane & 15, lk = lane >> 4;
    int sr = tid >> 3, sc = (tid & 7) * 8;

    f32x4 acc[4][2];
    #pragma unroll
    for (int i = 0; i < 4; ++i)
        #pragma unroll
        for (int j = 0; j < 2; ++j) acc[i][j] = (f32x4){0.f, 0.f, 0.f, 0.f};

    const ushort* Ap = xbf + (size_t)(b * T + sr) * D + sc;
    const ushort* Bp = w1t + (size_t)(h * 64 + sr) * D + sc;

    uint4 ra[4], rb[2];
    #pragma unroll
    for (int e = 0; e < 4; ++e) ra[e] = *(const uint4*)(Ap + (size_t)e * 32 * D);
    #pragma unroll
    for (int e = 0; e < 2; ++e) rb[e] = *(const uint4*)(Bp + (size_t)e * 32 * D);

    for (int k0 = 0; k0 < D; k0 += 64) {
        __syncthreads();
        #pragma unroll
        for (int e = 0; e < 4; ++e) *(uint4*)&AS_(sr + e * 32, sc) = ra[e];
        if (sr < 32) {
            #pragma unroll
            for (int e = 0; e < 2; ++e) *(uint4*)&BS_(sr + e * 32, sc) = rb[e];
        }
        __syncthreads();
        if (k0 + 64 < D) {
            #pragma unroll
            for (int e = 0; e < 4; ++e)
                ra[e] = *(const uint4*)(Ap + (size_t)e * 32 * D + k0 + 64);
            #pragma unroll
            for (int e = 0; e < 2; ++e)
                rb[e] = *(const uint4*)(Bp + (size_t)e * 32 * D + k0 + 64);
        }
        #pragma unroll
        for (int ks = 0; ks < 2; ++ks) {
            short8 af[4], bfr[2];
            #pragma unroll
            for (int i = 0; i < 4; ++i)
                af[i] = *(const short8*)&AS_(wm + i * 16 + lr, ks * 32 + lk * 8);
            #pragma unroll
            for (int j = 0; j < 2; ++j)
                bfr[j] = *(const short8*)&BS_(wn + j * 16 + lr, ks * 32 + lk * 8);
            #pragma unroll
            for (int i = 0; i < 4; ++i)
                #pragma unroll
                for (int j = 0; j < 2; ++j)
                    acc[i][j] = __builtin_amdgcn_mfma_f32_16x16x32_bf16(
                        af[i], bfr[j], acc[i][j], 0, 0, 0);
        }
    }

    #pragma unroll
    for (int j = 0; j < 2; ++j) {
        int col = wn + j * 16 + lr;
        float bv = b1[h * C1 + col];
        #pragma unroll
        for (int i = 0; i < 4; ++i) {
            int t0 = wm + i * 16 + lk * 4;
            union { ushort q[4]; uint2 v; } pk;
            #pragma unroll
            for (int r = 0; r < 4; ++r) pk.q[r] = f2bf(acc[i][j][r] + bv);
            *(uint2*)&WHT_(col, t0) = pk.v;
        }
    }
    __syncthreads();

    {
        int t = tid & 127;
        bool isS = tid < 128;
        const float* av = (isS ? a1s : a1d) + h * C1;
        float s = isS ? a1b[h] : 0.f;
        #pragma unroll 8
        for (int c = 0; c < 64; ++c) s = fmaf(bf2f(WHT_(c, t)), av[c], s);
        if (isS) ss[t] = s; else ddv[t] = s;
    }
    __syncthreads();

    {
        float dm = fmaxf(ddv[lane], ddv[lane + 64]);
        #pragma unroll
        for (int msk = 1; msk < 64; msk <<= 1) dm = fmaxf(dm, __shfl_xor(dm, msk));
        int i = tid >> 1, j0 = (tid & 1) * 64;
        float si = ss[i];
        float mx = si + dm; mx = mx >= 0.f ? mx : ALPHA * mx;
        float lsum = 0.f;
        #pragma unroll
        for (int g = 0; g < 8; ++g) {
            union { ushort q[8]; uint4 v; } pk;
            #pragma unroll
            for (int e = 0; e < 8; ++e) {
                float ee = si + ddv[j0 + g * 8 + e];
                ee = ee >= 0.f ? ee : ALPHA * ee;
                float pp = __expf(ee - mx);
                lsum += pp;
                pk.q[e] = f2bf(pp);
            }
            *(uint4*)&PB_(i, j0 + g * 8) = pk.v;
        }
        lsum += __shfl_xor(lsum, 1);
        if (!(tid & 1)) sinv[i] = 1.0f / lsum;
    }
    __syncthreads();

    f32x4 acc2[4][2];
    #pragma unroll
    for (int i = 0; i < 4; ++i)
        #pragma unroll
        for (int j = 0; j < 2; ++j) acc2[i][j] = (f32x4){0.f, 0.f, 0.f, 0.f};

    #pragma unroll
    for (int ks = 0; ks < 4; ++ks) {
        short8 af[4], bfr[2];
        #pragma unroll
        for (int i = 0; i < 4; ++i)
            af[i] = *(const short8*)&PB_(wm + i * 16 + lr, ks * 32 + lk * 8);
        #pragma unroll
        for (int j = 0; j < 2; ++j)
            bfr[j] = *(const short8*)&WHT_(wn + j * 16 + lr, ks * 32 + lk * 8);
        #pragma unroll
        for (int i = 0; i < 4; ++i)
            #pragma unroll
            for (int j = 0; j < 2; ++j)
                acc2[i][j] = __builtin_amdgcn_mfma_f32_16x16x32_bf16(
                    af[i], bfr[j], acc2[i][j], 0, 0, 0);
    }

    // ---- coalesced epilogue: restage in LDS (reuse Pb), then uint4 rows ----
    __syncthreads();                       // all PV ds_reads complete
    ushort* CT = u.Pb;                     // [128][72] (stride 72 => 16B align)
    #pragma unroll
    for (int i = 0; i < 4; ++i) {
        #pragma unroll
        for (int r = 0; r < 4; ++r) {
            int row = wm + i * 16 + lk * 4 + r;
            float sv = sinv[row];
            #pragma unroll
            for (int j = 0; j < 2; ++j) {
                int col = wn + j * 16 + lr;
                float v = acc2[i][j][r] * sv;
                v = v > 0.f ? v : 0.f;
                v = 1.0f / (1.0f + __expf(-v));
                CT[row * 72 + col] = f2bf(v);
            }
        }
    }
    __syncthreads();
    // 128 rows x 64 ushorts = 1024 uint4-chunks of 8 ushorts each.
    #pragma unroll
    for (int e = 0; e < 4; ++e) {
        int idx = e * 256 + tid;           // 0..1023: row = idx>>3, q = idx&7
        int row = idx >> 3, q = idx & 7;
        uint4 v = *(const uint4*)&CT[row * 72 + q * 8];
        *(uint4*)&c1[((size_t)(b * T + row)) * K2 + h * C1 + q * 8] = v;
    }
}

// ---------------------------------------------------------------------------
// FUSED kernel 2: split-K reduce (+bias) from PERMUTED partials -> scores ->
// P~ -> PV MFMA -> coalesced c2 write via LDS restage.
// ---------------------------------------------------------------------------
#define PB2_(r,c)  Pb2[(r) * 136 + (c)]
#define WHT2_(r,c) whT2[(r) * 136 + (c)]

__global__ __launch_bounds__(256) void fused2_kernel(
    const ushort* __restrict__ wh2pb,  // [8] x permuted [2048][1280] bf16
    const float* __restrict__ b2,      // [1280] ([h][c] flat)
    const float* __restrict__ a2s, const float* __restrict__ a2d,
    const float* __restrict__ a2b,
    ushort* __restrict__ c2)
{
    int blk = blockIdx.x; int b = blk >> 6, h = blk & 63;
    __shared__ ushort Pb2[128 * 136];
    __shared__ ushort whT2[32 * 136];
    __shared__ float ss[128], ddv[128], sinv[128];

    int tid = threadIdx.x;
    int wave = tid >> 6, lane = tid & 63;
    int lr = lane & 15, lk = lane >> 4;
    const size_t MNfull = (size_t)2048 * F2;

    // ---- load + split-K reduce (permuted layout) + transpose ----
    for (int e = 0; e < 10; ++e) {
        int idx = e * 256 + tid;               // 0..2559
        int t = idx / 20, c = idx - t * 20;
        int col = h * C2 + c;
        int tn = col >> 7, cl = col & 127;
        int wv = ((t >> 6) << 1) | (cl >> 6);
        int fi = (t >> 4) & 3, fk = (t >> 2) & 3, fr = t & 3;
        int fj = (cl >> 4) & 3, fl = cl & 15;
        size_t fa = (size_t)(b * 10 + tn) * 16384 + wv * 4096
                  + (fi * 4 + fj) * 256 + (fk * 16 + fl) * 4 + fr;
        float s = b2[col];
        #pragma unroll
        for (int p = 0; p < 8; ++p) s += bf2f(wh2pb[p * MNfull + fa]);
        WHT2_(c, t) = f2bf(s);
    }
    {   // zero-pad rows 20..31
        int idx = tid;
        for (int e = 0; e < 6; ++e, idx += 256) {
            int c = 20 + (idx >> 7), t = idx & 127;
            WHT2_(c, t) = 0;
        }
    }
    __syncthreads();

    // ---- scores ----
    {
        int t = tid & 127;
        bool isS = tid < 128;
        const float* av = (isS ? a2s : a2d) + h * C2;
        float s = isS ? a2b[h] : 0.f;
        #pragma unroll
        for (int c = 0; c < 20; ++c) s = fmaf(bf2f(WHT2_(c, t)), av[c], s);
        if (isS) ss[t] = s; else ddv[t] = s;
    }
    __syncthreads();

    // ---- P~ + row sums ----
    {
        float dm = fmaxf(ddv[lane], ddv[lane + 64]);
        #pragma unroll
        for (int msk = 1; msk < 64; msk <<= 1) dm = fmaxf(dm, __shfl_xor(dm, msk));
        int i = tid >> 1, j0 = (tid & 1) * 64;
        float si = ss[i];
        float mx = si + dm; mx = mx >= 0.f ? mx : ALPHA * mx;
        float lsum = 0.f;
        #pragma unroll
        for (int g = 0; g < 8; ++g) {
            union { ushort q[8]; uint4 v; } pk;
            #pragma unroll
            for (int e = 0; e < 8; ++e) {
                float ee = si + ddv[j0 + g * 8 + e];
                ee = ee >= 0.f ? ee : ALPHA * ee;
                float pp = __expf(ee - mx);
                lsum += pp;
                pk.q[e] = f2bf(pp);
            }
            *(uint4*)&PB2_(i, j0 + g * 8) = pk.v;
        }
        lsum += __shfl_xor(lsum, 1);
        if (!(tid & 1)) sinv[i] = 1.0f / lsum;
    }
    __syncthreads();

    // ---- PV: out[128][32] = P~ @ whT2^T; wave owns 32 rows ----
    int wm2 = wave * 32;
    f32x4 acc2[2][2];
    #pragma unroll
    for (int i = 0; i < 2; ++i)
        #pragma unroll
        for (int j = 0; j < 2; ++j) acc2[i][j] = (f32x4){0.f, 0.f, 0.f, 0.f};

    #pragma unroll
    for (int ks = 0; ks < 4; ++ks) {
        short8 af[2], bfr[2];
        #pragma unroll
        for (int i = 0; i < 2; ++i)
            af[i] = *(const short8*)&PB2_(wm2 + i * 16 + lr, ks * 32 + lk * 8);
        #pragma unroll
        for (int j = 0; j < 2; ++j)
            bfr[j] = *(const short8*)&WHT2_(j * 16 + lr, ks * 32 + lk * 8);
        #pragma unroll
        for (int i = 0; i < 2; ++i)
            #pragma unroll
            for (int j = 0; j < 2; ++j)
                acc2[i][j] = __builtin_amdgcn_mfma_f32_16x16x32_bf16(
                    af[i], bfr[j], acc2[i][j], 0, 0, 0);
    }

    // ---- coalesced epilogue via LDS restage (reuse Pb2) ----
    __syncthreads();
    ushort* CT2 = Pb2;                     // [128][24]
    #pragma unroll
    for (int i = 0; i < 2; ++i) {
        #pragma unroll
        for (int r = 0; r < 4; ++r) {
            int row = wm2 + i * 16 + lk * 4 + r;
            float sv = sinv[row];
            #pragma unroll
            for (int j = 0; j < 2; ++j) {
                int col = j * 16 + lr;
                if (col < C2) {
                    float v = acc2[i][j][r] * sv;
                    v = v > 0.f ? v : 0.f;
                    v = 1.0f / (1.0f + __expf(-v));
                    CT2[row * 24 + col] = f2bf(v);
                }
            }
        }
    }
    __syncthreads();
    for (int e = 0; e < 3; ++e) {
        int idx = e * 256 + tid;           // 0..639: row = idx/5, q = idx%5
        if (idx < 640) {
            int row = idx / 5, q = idx - row * 5;
            uint2 v = *(const uint2*)&CT2[row * 24 + q * 4];
            *(uint2*)&c2[((size_t)(b * T + row)) * F2 + h * C2 + q * 4] = v;
        }
    }
}

// ---------------------------------------------------------------------------
// Prep kernels
// ---------------------------------------------------------------------------
__global__ __launch_bounds__(256) void xbf_kernel(
    const float* __restrict__ x, ushort* __restrict__ xbf)
{
    int i = blockIdx.x * 256 + threadIdx.x;
    float4 v = *(const float4*)&x[(size_t)i * 4];
    union { ushort u[4]; uint2 p; } o;
    o.u[0] = f2bf(v.x); o.u[1] = f2bf(v.y);
    o.u[2] = f2bf(v.z); o.u[3] = f2bf(v.w);
    *(uint2*)&xbf[(size_t)i * 4] = o.p;
}

__global__ __launch_bounds__(256) void w1t_kernel(
    const float* __restrict__ W1, ushort* __restrict__ w1t)
{
    int blk = blockIdx.x; int h = blk >> 2, d0 = (blk & 3) * 64;
    __shared__ float lw[64][65];
    int tid = threadIdx.x;
    for (int e = 0; e < 16; ++e) {
        int idx = e * 256 + tid; int dr = idx >> 6, c = idx & 63;
        lw[dr][c] = W1[((size_t)h * D + d0 + dr) * C1 + c];
    }
    __syncthreads();
    for (int e = 0; e < 16; ++e) {
        int idx = e * 256 + tid; int c = idx >> 6, dr = idx & 63;
        w1t[((size_t)(h * 64 + c)) * D + d0 + dr] = f2bf(lw[dr][c]);
    }
}

__global__ __launch_bounds__(256) void w2t_kernel(
    const float* __restrict__ W2, ushort* __restrict__ w2t)
{
    int blk = blockIdx.x; int h = blk >> 5, kb = blk & 31; int k0 = kb * 128;
    __shared__ float lw[128][21];
    int tid = threadIdx.x;
    const float* src = W2 + ((size_t)h * K2 + k0) * C2;
    for (int e = 0; e < 10; ++e) {
        int idx = e * 256 + tid; int k = idx / 20, c = idx - k * 20;
        lw[k][c] = src[idx];
    }
    __syncthreads();
    for (int e = 0; e < 10; ++e) {
        int idx = e * 256 + tid; int c = idx >> 7, k = idx & 127;
        w2t[((size_t)(h * 20 + c)) * K2 + k0 + k] = f2bf(lw[k][c]);
    }
}

__global__ __launch_bounds__(256) void slwt_kernel(
    const float* __restrict__ slw, ushort* __restrict__ slwt)
{
    int blk = blockIdx.x; int kb = blk >> 2, d0 = (blk & 3) * 64; int k0 = kb * 64;
    __shared__ float lw[64][65];
    int tid = threadIdx.x;
    for (int e = 0; e < 16; ++e) {
        int idx = e * 256 + tid; int kr = idx >> 6, dc = idx & 63;
        lw[kr][dc] = slw[((size_t)(k0 + kr)) * D + d0 + dc];
    }
    __syncthreads();
    for (int e = 0; e < 16; ++e) {
        int idx = e * 256 + tid; int dr = idx >> 6, kc = idx & 63;
        slwt[((size_t)(d0 + dr)) * F2 + k0 + kc] = f2bf(lw[kc][dr]);
    }
}

// ---------------------------------------------------------------------------
// GAR: res[b,o,d] = sum_t c3[b,t,d]*gar_w[t,o] + gar_b[o]
// ---------------------------------------------------------------------------
__global__ __launch_bounds__(256) void gar_kernel(
    const float* __restrict__ c3, const float* __restrict__ garw,
    const float* __restrict__ garb, float* __restrict__ out)
{
    int blk = blockIdx.x; int b = blk >> 5, o = blk & 31;
    int dcol = threadIdx.x;
    float acc = garb[o];
    const float* cp = c3 + (size_t)b * T * D + dcol;
    for (int t = 0; t < T; ++t)
        acc = fmaf(cp[(size_t)t * D], garw[t * OUTW + o], acc);
    out[((size_t)b * OUTW + o) * D + dcol] = acc;
}

// ---------------------------------------------------------------------------
extern "C" void kernel_launch(void* const* d_in, const int* in_sizes, int n_in,
                              void* d_out, int out_size, void* d_ws, size_t ws_size,
                              hipStream_t stream) {
    const float* x    = (const float*)d_in[0];
    const float* W1   = (const float*)d_in[1];
    const float* b1   = (const float*)d_in[2];
    const float* a1s  = (const float*)d_in[3];
    const float* a1d  = (const float*)d_in[4];
    const float* a1b  = (const float*)d_in[5];
    const float* W2   = (const float*)d_in[6];
    const float* b2   = (const float*)d_in[7];
    const float* a2s  = (const float*)d_in[8];
    const float* a2d  = (const float*)d_in[9];
    const float* a2b  = (const float*)d_in[10];
    const float* slw  = (const float*)d_in[11];
    const float* slb  = (const float*)d_in[12];
    const float* garw = (const float*)d_in[13];
    const float* garb = (const float*)d_in[14];

    char* p = (char*)d_ws;
    float*  c3    = (float*)p;   p += (size_t)2048 * 256  * 4;     //  2.1 MB
    ushort* xbf   = (ushort*)p;  p += (size_t)2048 * 256  * 2;     //  1.0 MB
    ushort* w1t   = (ushort*)p;  p += (size_t)4096 * 256  * 2;     //  2.1 MB
    ushort* c1bf  = (ushort*)p;  p += (size_t)2048 * 4096 * 2;     // 16.8 MB
    ushort* w2t   = (ushort*)p;  p += (size_t)1280 * 4096 * 2;     // 10.5 MB
    ushort* c2bf  = (ushort*)p;  p += (size_t)2048 * 1280 * 2;     //  5.2 MB
    ushort* slwt  = (ushort*)p;  p += (size_t)256  * 1280 * 2;     //  0.7 MB
    ushort* wh2pb = (ushort*)p;  p += (size_t)8 * 2048 * 1280 * 2; // 42 MB
    ushort* c3pb  = (ushort*)c1bf;   // aliases c1bf (dead after gemm2 reads it)

    xbf_kernel <<<512,  256, 0, stream>>>(x, xbf);
    w1t_kernel <<<256,  256, 0, stream>>>(W1, w1t);
    w2t_kernel <<<2048, 256, 0, stream>>>(W2, w2t);
    slwt_kernel<<<80,   256, 0, stream>>>(slw, slwt);

    fused1_kernel<<<B * H, 256, 0, stream>>>(xbf, w1t, b1, a1s, a1d, a1b, c1bf);

    gemm_splitk_kernel<4096, 10, 16, 8, 1><<<1280, 256, 0, stream>>>(c1bf, w2t,
                                                                     wh2pb);
    fused2_kernel<<<B * H, 256, 0, stream>>>(wh2pb, b2, a2s, a2d, a2b, c2bf);

    gemm_splitk_kernel<1280, 2, 16, 4, 0><<<128, 256, 0, stream>>>(c2bf, slwt,
                                                                   c3pb);
    reduce_bias_kernel<4, 256><<<512, 256, 0, stream>>>(c3pb, slb, c3, 2048 * 256);

    gar_kernel<<<B * OUTW, 256, 0, stream>>>(c3, garw, garb, (float*)d_out);
}